// Round 2
// baseline (1625.328 us; speedup 1.0000x reference)
//
#include <hip/hip_runtime.h>
#include <math.h>

#define HID 128

__device__ __forceinline__ float leaky02(float z) { return z >= 0.f ? z : 0.2f * z; }

// ---------------- node encoder: h = relu(concat(feat) @ W_in + b_in) ----------------
__global__ void k_enc(const float* __restrict__ nodenum, const int* __restrict__ c0,
                      const int* __restrict__ c1, const int* __restrict__ batch,
                      const float* __restrict__ recipe,
                      const float* __restrict__ e0, const float* __restrict__ e1,
                      const float* __restrict__ Win, const float* __restrict__ bin,
                      float* __restrict__ h, int n) {
  __shared__ float W[38 * 128];
  __shared__ float bsh[128];
  __shared__ float f[8][38];
  int t = threadIdx.x;  // 256
  for (int i = t; i < 38 * 128; i += 256) W[i] = Win[i];
  if (t < 128) bsh[t] = bin[t];
  __syncthreads();
  for (int base = blockIdx.x * 8; base < n; base += gridDim.x * 8) {
    int nn = min(8, n - base);
    for (int idx = t; idx < nn * 38; idx += 256) {
      int r = idx / 38, k = idx - r * 38;
      int v = base + r;
      float val;
      if (k < 8) val = nodenum[v * 8 + k];
      else if (k < 14) val = e0[c0[v] * 6 + (k - 8)];
      else if (k < 22) val = e1[c1[v] * 8 + (k - 14)];
      else val = recipe[batch[v] * 16 + (k - 22)];
      f[r][k] = val;
    }
    __syncthreads();
    int col = t & 127;
    int rbase = (t >> 7) * 4;  // 0 or 4
    float acc[4] = {0.f, 0.f, 0.f, 0.f};
    for (int k = 0; k < 38; k++) {
      float w = W[k * 128 + col];
#pragma unroll
      for (int r = 0; r < 4; r++) acc[r] += f[rbase + r][k] * w;
    }
#pragma unroll
    for (int r = 0; r < 4; r++) {
      int v = base + rbase + r;
      if (v < n) h[v * HID + col] = fmaxf(acc[r] + bsh[col], 0.f);
    }
    __syncthreads();
  }
}

// ---------------- precompute P_l (18x4), q_l (4): a_e = raw @ P + q ----------------
__global__ void k_prep(const float* __restrict__ gle, const float* __restrict__ atte,
                       const float* __restrict__ We, const float* __restrict__ be,
                       float* __restrict__ P, float* __restrict__ q) {
  __shared__ float M[128 * 4];
  int t = threadIdx.x;  // 128
  for (int l = 0; l < 3; l++) {
    {
      int k = t;
#pragma unroll
      for (int hh = 0; hh < 4; hh++) {
        float acc = 0.f;
        for (int c = 0; c < 32; c++)
          acc += gle[l * 16384 + k * 128 + hh * 32 + c] * atte[l * 128 + hh * 32 + c];
        M[k * 4 + hh] = acc;
      }
    }
    __syncthreads();
    if (t < 72) {
      int j = t >> 2, hh = t & 3;
      float acc = 0.f;
      for (int k = 0; k < 128; k++) acc += We[j * 128 + k] * M[k * 4 + hh];
      P[(l * 18 + j) * 4 + hh] = acc;
    }
    if (t < 4) {
      float acc = 0.f;
      for (int k = 0; k < 128; k++) acc += be[k] * M[k * 4 + t];
      q[l * 4 + t] = acc;
    }
    __syncthreads();
  }
}

// ------- per-edge a_e for all 3 layers + scatter sums for self-loop mean + degree -------
__global__ void k_ae(const float* __restrict__ enum_, const int* __restrict__ ec0,
                     const int* __restrict__ ec1, const int* __restrict__ dst,
                     const float* __restrict__ ee0, const float* __restrict__ ee1,
                     const float* __restrict__ P, const float* __restrict__ q,
                     float* __restrict__ ae, float* __restrict__ sum_ae,
                     int* __restrict__ cnt, int E) {
  __shared__ float Ps[216];
  __shared__ float qs[12];
  int t = threadIdx.x;
  for (int i = t; i < 216; i += 256) Ps[i] = P[i];
  if (t < 12) qs[t] = q[t];
  __syncthreads();
  int i = blockIdx.x * 256 + t;
  if (i >= E) return;
  float raw[18];
  float4 nm = *(const float4*)(enum_ + (size_t)i * 4);
  raw[0] = nm.x; raw[1] = nm.y; raw[2] = nm.z; raw[3] = nm.w;
  int a0 = ec0[i], a1 = ec1[i];
  float4 eb0 = *(const float4*)(ee0 + a0 * 4);
  raw[4] = eb0.x; raw[5] = eb0.y; raw[6] = eb0.z; raw[7] = eb0.w;
#pragma unroll
  for (int j = 0; j < 10; j++) raw[8 + j] = ee1[a1 * 10 + j];
  int d = dst[i];
#pragma unroll
  for (int l = 0; l < 3; l++) {
    float o[4];
#pragma unroll
    for (int hh = 0; hh < 4; hh++) {
      float acc = qs[l * 4 + hh];
#pragma unroll
      for (int j = 0; j < 18; j++) acc += raw[j] * Ps[(l * 18 + j) * 4 + hh];
      o[hh] = acc;
    }
    *(float4*)(ae + (size_t)i * 12 + l * 4) = make_float4(o[0], o[1], o[2], o[3]);
#pragma unroll
    for (int hh = 0; hh < 4; hh++) atomicAdd(&sum_ae[(size_t)d * 12 + l * 4 + hh], o[hh]);
  }
  atomicAdd(&cnt[d], 1);
}

// self-loop a_e = mean of incoming a_e  (sum_ae normalized in place)
__global__ void k_loopae(float* __restrict__ sum_ae, const int* __restrict__ cnt, int n) {
  int i = blockIdx.x * 256 + threadIdx.x;
  if (i >= n) return;
  float inv = 1.f / fmaxf((float)cnt[i], 1.f);
#pragma unroll
  for (int m = 0; m < 12; m++) sum_ae[(size_t)i * 12 + m] *= inv;
}

// ---------------- CSR build: exclusive scan of cnt -> rowptr, then fill ----------------
__global__ void k_scan1(const int* __restrict__ cnt, int* __restrict__ excl,
                        int* __restrict__ bsum, int n) {
  __shared__ int sh[256];
  int t = threadIdx.x;
  int i = blockIdx.x * 256 + t;
  int v = (i < n) ? cnt[i] : 0;
  sh[t] = v;
  __syncthreads();
  for (int off = 1; off < 256; off <<= 1) {
    int add = (t >= off) ? sh[t - off] : 0;
    __syncthreads();
    sh[t] += add;
    __syncthreads();
  }
  if (i < n) excl[i] = sh[t] - v;
  if (t == 255) bsum[blockIdx.x] = sh[255];
}

__global__ void k_scan2(int* __restrict__ bsum, int nb) {
  __shared__ int sh[512];
  int t = threadIdx.x;
  int v = (t < nb) ? bsum[t] : 0;
  sh[t] = v;
  __syncthreads();
  for (int off = 1; off < 512; off <<= 1) {
    int add = (t >= off) ? sh[t - off] : 0;
    __syncthreads();
    sh[t] += add;
    __syncthreads();
  }
  if (t < nb) bsum[t] = sh[t] - v;
}

__global__ void k_scan3(int* __restrict__ rowptr, const int* __restrict__ boff,
                        int* __restrict__ cursor, int n, int E) {
  int i = blockIdx.x * 256 + threadIdx.x;
  if (i < n) {
    int val = rowptr[i] + boff[i >> 8];
    rowptr[i] = val;
    cursor[i] = val;
  }
  if (i == 0) rowptr[n] = E;
}

__global__ void k_fill(const int* __restrict__ dst, int* __restrict__ cursor,
                       int* __restrict__ csr, int E) {
  int i = blockIdx.x * 256 + threadIdx.x;
  if (i >= E) return;
  int pos = atomicAdd(&cursor[dst[i]], 1);
  csr[pos] = i;
}

// ---------------- x = h @ gat_lin[l]  (col-half per block.y, 32 rows/iter) ----------------
__global__ void k_x(const float* __restrict__ h, const float* __restrict__ L_g,
                    float* __restrict__ x, int n) {
  __shared__ float L[128 * 64];
  __shared__ float hr[32][128];
  int t = threadIdx.x;  // 256
  int ch = blockIdx.y;  // col half 0/1
  for (int i = t; i < 128 * 64; i += 256) {
    int k = i >> 6, c = i & 63;
    L[i] = L_g[k * 128 + ch * 64 + c];
  }
  __syncthreads();
  int col = t & 63;
  int rb = (t >> 6) * 8;  // 0,8,16,24
  for (int base = blockIdx.x * 32; base < n; base += gridDim.x * 32) {
    int nr = min(32, n - base);
    for (int i = t; i < nr * 128; i += 256) hr[i >> 7][i & 127] = h[(size_t)base * 128 + i];
    __syncthreads();
    float acc[8] = {0.f, 0.f, 0.f, 0.f, 0.f, 0.f, 0.f, 0.f};
    for (int k = 0; k < 128; k++) {
      float w = L[k * 64 + col];
#pragma unroll
      for (int r = 0; r < 8; r++) acc[r] += hr[rb + r][k] * w;
    }
#pragma unroll
    for (int r = 0; r < 8; r++) {
      int v = base + rb + r;
      if (v < n) x[(size_t)v * 128 + ch * 64 + col] = acc[r];
    }
    __syncthreads();
  }
}

// ---------------- a_s, a_d: per-head dot of x row with att vectors ----------------
__global__ void k_att(const float* __restrict__ x, const float* __restrict__ att_s,
                      const float* __restrict__ att_d, float* __restrict__ a_s,
                      float* __restrict__ a_d, int n) {
  int t = threadIdx.x;  // 256
  int j = t & 127;
  float asv = att_s[j];
  float adv = att_d[j];
  int half = t >> 7;
  for (int vb = blockIdx.x * 2; vb < n; vb += gridDim.x * 2) {
    int v = vb + half;
    if (v < n) {
      float xv = x[(size_t)v * 128 + j];
      float ps = xv * asv, pd = xv * adv;
#pragma unroll
      for (int m = 16; m >= 1; m >>= 1) {
        ps += __shfl_xor(ps, m);
        pd += __shfl_xor(pd, m);
      }
      if ((j & 31) == 0) {
        a_s[(size_t)v * 4 + (j >> 5)] = ps;
        a_d[(size_t)v * 4 + (j >> 5)] = pd;
      }
    }
  }
}

// -------- per-dst online softmax + weighted gather; one wave per node; h updated in place --------
__global__ void k_agg(const float* __restrict__ x, const float* __restrict__ a_s,
                      const float* __restrict__ a_d, const float* __restrict__ ae,
                      const float* __restrict__ ae_loop,
                      const int* __restrict__ rowptr, const int* __restrict__ csr,
                      const int* __restrict__ srcarr, const float* __restrict__ bias,
                      float* __restrict__ hout, int n, int l) {
  int wid = threadIdx.x >> 6;
  int v = blockIdx.x * 4 + wid;
  if (v >= n) return;
  int lane = threadIdx.x & 63;
  float4 ad = *(const float4*)(a_d + (size_t)v * 4);
  float4 aeL = *(const float4*)(ae_loop + (size_t)v * 12 + l * 4);
  float4 asv = *(const float4*)(a_s + (size_t)v * 4);
  float m0 = leaky02(asv.x + ad.x + aeL.x);
  float m1 = leaky02(asv.y + ad.y + aeL.y);
  float m2 = leaky02(asv.z + ad.z + aeL.z);
  float m3 = leaky02(asv.w + ad.w + aeL.w);
  float s0 = 1.f, s1 = 1.f, s2 = 1.f, s3 = 1.f;
  float acc0 = x[(size_t)v * HID + lane];
  float acc1 = x[(size_t)v * HID + 64 + lane];
  int beg = rowptr[v], end = rowptr[v + 1];
  bool hi = (lane & 32) != 0;
  for (int j = beg; j < end; j++) {
    int eid = csr[j];
    int src = srcarr[eid];
    float4 aev = *(const float4*)(ae + (size_t)eid * 12 + l * 4);
    float4 asrc = *(const float4*)(a_s + (size_t)src * 4);
    float l0 = leaky02(asrc.x + ad.x + aev.x);
    float l1 = leaky02(asrc.y + ad.y + aev.y);
    float l2 = leaky02(asrc.z + ad.z + aev.z);
    float l3 = leaky02(asrc.w + ad.w + aev.w);
    float x0 = x[(size_t)src * HID + lane];
    float x1 = x[(size_t)src * HID + 64 + lane];
    float n0 = fmaxf(m0, l0), n1 = fmaxf(m1, l1), n2 = fmaxf(m2, l2), n3 = fmaxf(m3, l3);
    float c0 = __expf(m0 - n0), c1 = __expf(m1 - n1), c2 = __expf(m2 - n2), c3 = __expf(m3 - n3);
    float p0 = __expf(l0 - n0), p1 = __expf(l1 - n1), p2 = __expf(l2 - n2), p3 = __expf(l3 - n3);
    s0 = s0 * c0 + p0; s1 = s1 * c1 + p1; s2 = s2 * c2 + p2; s3 = s3 * c3 + p3;
    m0 = n0; m1 = n1; m2 = n2; m3 = n3;
    float cA = hi ? c1 : c0, pA = hi ? p1 : p0;
    float cB = hi ? c3 : c2, pB = hi ? p3 : p2;
    acc0 = acc0 * cA + pA * x0;
    acc1 = acc1 * cB + pB * x1;
  }
  float sA = hi ? s1 : s0;
  float sB = hi ? s3 : s2;
  float r0 = acc0 / sA + bias[l * HID + lane];
  float r1 = acc1 / sB + bias[l * HID + 64 + lane];
  hout[(size_t)v * HID + lane] = fmaxf(r0, 0.f);
  hout[(size_t)v * HID + 64 + lane] = fmaxf(r1, 0.f);
}

// ---------------- pooling: batch is sorted -> register accumulate, flush on change ----------------
__global__ void k_pool(const float* __restrict__ h, const int* __restrict__ batch,
                       float* __restrict__ g, int n) {
  int t = threadIdx.x;  // 128
  int per = (n + gridDim.x - 1) / gridDim.x;
  int start = blockIdx.x * per;
  int end = min(n, start + per);
  float acc = 0.f;
  int cur = -1;
  for (int v = start; v < end; v++) {
    int b = batch[v];
    if (b != cur) {
      if (cur >= 0) atomicAdd(&g[cur * 128 + t], acc);
      acc = 0.f;
      cur = b;
    }
    acc += h[(size_t)v * 128 + t];
  }
  if (cur >= 0) atomicAdd(&g[cur * 128 + t], acc);
}

// ---------------- head MLP on pooled g (8x128) ----------------
__global__ void k_head(const float* __restrict__ g, const float* __restrict__ Wr1,
                       const float* __restrict__ br1, const float* __restrict__ Wr2,
                       const float* __restrict__ br2, float* __restrict__ out, int G_) {
  __shared__ float gl[8 * 128];
  __shared__ float red[128];
  int t = threadIdx.x;  // 128
  for (int i = t; i < G_ * 128; i += 128) gl[i] = g[i];
  __syncthreads();
  for (int i = 0; i < G_; i++) {
    float acc = br1[t];
    for (int k = 0; k < 128; k++) acc += gl[i * 128 + k] * Wr1[k * 128 + t];
    float hv = fmaxf(acc, 0.f);
    red[t] = hv * Wr2[t];
    __syncthreads();
    if (t == 0) {
      float s = br2[0];
      for (int k = 0; k < 128; k++) s += red[k];
      out[i] = s;
    }
    __syncthreads();
  }
}

extern "C" void kernel_launch(void* const* d_in, const int* in_sizes, int n_in,
                              void* d_out, int out_size, void* d_ws, size_t ws_size,
                              hipStream_t stream) {
  const float* node_numeric = (const float*)d_in[0];
  const int* node_cat0 = (const int*)d_in[1];
  const int* node_cat1 = (const int*)d_in[2];
  const float* edge_numeric = (const float*)d_in[3];
  const int* edge_cat0 = (const int*)d_in[4];
  const int* edge_cat1 = (const int*)d_in[5];
  const int* edge_index = (const int*)d_in[6];
  const int* batch = (const int*)d_in[7];
  const float* recipe = (const float*)d_in[8];
  const float* emb_node0 = (const float*)d_in[9];
  const float* emb_node1 = (const float*)d_in[10];
  const float* emb_edge0 = (const float*)d_in[11];
  const float* emb_edge1 = (const float*)d_in[12];
  const float* W_in = (const float*)d_in[13];
  const float* b_in = (const float*)d_in[14];
  const float* W_edge = (const float*)d_in[15];
  const float* b_edge = (const float*)d_in[16];
  const float* gat_lin = (const float*)d_in[17];
  const float* gat_lin_edge = (const float*)d_in[18];
  const float* att_src = (const float*)d_in[19];
  const float* att_dst = (const float*)d_in[20];
  const float* att_edge = (const float*)d_in[21];
  const float* gat_bias = (const float*)d_in[22];
  const float* W_r1 = (const float*)d_in[23];
  const float* b_r1 = (const float*)d_in[24];
  const float* W_r2 = (const float*)d_in[25];
  const float* b_r2 = (const float*)d_in[26];

  int N = in_sizes[0] / 8;
  int E = in_sizes[3] / 4;
  int Gn = in_sizes[8] / 16;
  const int* srcArr = edge_index;
  const int* dstArr = edge_index + E;

  char* ws = (char*)d_ws;
  size_t o = 0;
  auto alloc = [&](size_t b) {
    char* p = ws + o;
    o = (o + b + 255) & ~(size_t)255;
    return p;
  };
  float* h = (float*)alloc((size_t)N * 128 * 4);
  float* x = (float*)alloc((size_t)N * 128 * 4);
  float* ae = (float*)alloc((size_t)E * 12 * 4);
  float* aeL = (float*)alloc((size_t)N * 12 * 4);
  float* a_s = (float*)alloc((size_t)N * 4 * 4);
  float* a_d = (float*)alloc((size_t)N * 4 * 4);
  float* P = (float*)alloc(216 * 4);
  float* q = (float*)alloc(12 * 4);
  int* cnt = (int*)alloc((size_t)N * 4);
  int* rowptr = (int*)alloc((size_t)(N + 1) * 4);
  int* cursor = (int*)alloc((size_t)N * 4);
  int* bsum = (int*)alloc(512 * 4);
  int* csr = (int*)alloc((size_t)E * 4);
  float* g = (float*)alloc((size_t)Gn * 128 * 4);
  (void)ws_size;

  (void)hipMemsetAsync(cnt, 0, (size_t)N * 4, stream);
  (void)hipMemsetAsync(aeL, 0, (size_t)N * 12 * 4, stream);
  (void)hipMemsetAsync(g, 0, (size_t)Gn * 128 * 4, stream);

  int nbl = (N + 255) / 256;
  int ebl = (E + 255) / 256;

  k_enc<<<512, 256, 0, stream>>>(node_numeric, node_cat0, node_cat1, batch, recipe,
                                 emb_node0, emb_node1, W_in, b_in, h, N);
  k_prep<<<1, 128, 0, stream>>>(gat_lin_edge, att_edge, W_edge, b_edge, P, q);
  k_ae<<<ebl, 256, 0, stream>>>(edge_numeric, edge_cat0, edge_cat1, dstArr,
                                emb_edge0, emb_edge1, P, q, ae, aeL, cnt, E);
  k_loopae<<<nbl, 256, 0, stream>>>(aeL, cnt, N);
  k_scan1<<<nbl, 256, 0, stream>>>(cnt, rowptr, bsum, N);
  k_scan2<<<1, 512, 0, stream>>>(bsum, nbl);
  k_scan3<<<nbl, 256, 0, stream>>>(rowptr, bsum, cursor, N, E);
  k_fill<<<ebl, 256, 0, stream>>>(dstArr, cursor, csr, E);

  for (int l = 0; l < 3; l++) {
    dim3 gx(512, 2);
    k_x<<<gx, 256, 0, stream>>>(h, gat_lin + l * 16384, x, N);
    k_att<<<1024, 256, 0, stream>>>(x, att_src + l * 128, att_dst + l * 128, a_s, a_d, N);
    k_agg<<<(N + 3) / 4, 256, 0, stream>>>(x, a_s, a_d, ae, aeL, rowptr, csr, srcArr,
                                           gat_bias, h, N, l);
  }
  k_pool<<<512, 128, 0, stream>>>(h, batch, g, N);
  k_head<<<1, 128, 0, stream>>>(g, W_r1, b_r1, W_r2, b_r2, (float*)d_out, Gn);
}

// Round 3
// 1281.534 us; speedup vs baseline: 1.2683x; 1.2683x over previous
//
#include <hip/hip_runtime.h>
#include <math.h>

#define HID 128

__device__ __forceinline__ float leaky02(float z) { return z >= 0.f ? z : 0.2f * z; }

// ---------------- node encoder: h = relu(concat(feat) @ W_in + b_in) ----------------
__global__ void k_enc(const float* __restrict__ nodenum, const int* __restrict__ c0,
                      const int* __restrict__ c1, const int* __restrict__ batch,
                      const float* __restrict__ recipe,
                      const float* __restrict__ e0, const float* __restrict__ e1,
                      const float* __restrict__ Win, const float* __restrict__ bin,
                      float* __restrict__ h, int n) {
  __shared__ float W[38 * 128];
  __shared__ float bsh[128];
  __shared__ float f[8][38];
  int t = threadIdx.x;  // 256
  for (int i = t; i < 38 * 128; i += 256) W[i] = Win[i];
  if (t < 128) bsh[t] = bin[t];
  __syncthreads();
  for (int base = blockIdx.x * 8; base < n; base += gridDim.x * 8) {
    int nn = min(8, n - base);
    for (int idx = t; idx < nn * 38; idx += 256) {
      int r = idx / 38, k = idx - r * 38;
      int v = base + r;
      float val;
      if (k < 8) val = nodenum[v * 8 + k];
      else if (k < 14) val = e0[c0[v] * 6 + (k - 8)];
      else if (k < 22) val = e1[c1[v] * 8 + (k - 14)];
      else val = recipe[batch[v] * 16 + (k - 22)];
      f[r][k] = val;
    }
    __syncthreads();
    int col = t & 127;
    int rbase = (t >> 7) * 4;  // 0 or 4
    float acc[4] = {0.f, 0.f, 0.f, 0.f};
    for (int k = 0; k < 38; k++) {
      float w = W[k * 128 + col];
#pragma unroll
      for (int r = 0; r < 4; r++) acc[r] += f[rbase + r][k] * w;
    }
#pragma unroll
    for (int r = 0; r < 4; r++) {
      int v = base + rbase + r;
      if (v < n) h[v * HID + col] = fmaxf(acc[r] + bsh[col], 0.f);
    }
    __syncthreads();
  }
}

// ---------------- precompute P_l (18x4), q_l (4): a_e = raw @ P + q ----------------
__global__ void k_prep(const float* __restrict__ gle, const float* __restrict__ atte,
                       const float* __restrict__ We, const float* __restrict__ be,
                       float* __restrict__ P, float* __restrict__ q) {
  __shared__ float M[128 * 4];
  int t = threadIdx.x;  // 128
  for (int l = 0; l < 3; l++) {
    {
      int k = t;
#pragma unroll
      for (int hh = 0; hh < 4; hh++) {
        float acc = 0.f;
        for (int c = 0; c < 32; c++)
          acc += gle[l * 16384 + k * 128 + hh * 32 + c] * atte[l * 128 + hh * 32 + c];
        M[k * 4 + hh] = acc;
      }
    }
    __syncthreads();
    if (t < 72) {
      int j = t >> 2, hh = t & 3;
      float acc = 0.f;
      for (int k = 0; k < 128; k++) acc += We[j * 128 + k] * M[k * 4 + hh];
      P[(l * 18 + j) * 4 + hh] = acc;
    }
    if (t < 4) {
      float acc = 0.f;
      for (int k = 0; k < 128; k++) acc += be[k] * M[k * 4 + t];
      q[l * 4 + t] = acc;
    }
    __syncthreads();
  }
}

// ---------------- degree histogram (int atomics only) ----------------
__global__ void k_deg(const int* __restrict__ dst, int* __restrict__ cnt, int E) {
  int i = blockIdx.x * 256 + threadIdx.x;
  if (i < E) atomicAdd(&cnt[dst[i]], 1);
}

// ------- per-edge a_e for all 3 layers (pure streaming, no atomics) -------
__global__ void k_ae(const float* __restrict__ enum_, const int* __restrict__ ec0,
                     const int* __restrict__ ec1,
                     const float* __restrict__ ee0, const float* __restrict__ ee1,
                     const float* __restrict__ P, const float* __restrict__ q,
                     float* __restrict__ ae, int E) {
  __shared__ float Ps[216];
  __shared__ float qs[12];
  int t = threadIdx.x;
  for (int i = t; i < 216; i += 256) Ps[i] = P[i];
  if (t < 12) qs[t] = q[t];
  __syncthreads();
  int i = blockIdx.x * 256 + t;
  if (i >= E) return;
  float raw[18];
  float4 nm = *(const float4*)(enum_ + (size_t)i * 4);
  raw[0] = nm.x; raw[1] = nm.y; raw[2] = nm.z; raw[3] = nm.w;
  int a0 = ec0[i], a1 = ec1[i];
  float4 eb0 = *(const float4*)(ee0 + a0 * 4);
  raw[4] = eb0.x; raw[5] = eb0.y; raw[6] = eb0.z; raw[7] = eb0.w;
#pragma unroll
  for (int j = 0; j < 10; j++) raw[8 + j] = ee1[a1 * 10 + j];
#pragma unroll
  for (int l = 0; l < 3; l++) {
    float o[4];
#pragma unroll
    for (int hh = 0; hh < 4; hh++) {
      float acc = qs[l * 4 + hh];
#pragma unroll
      for (int j = 0; j < 18; j++) acc += raw[j] * Ps[(l * 18 + j) * 4 + hh];
      o[hh] = acc;
    }
    *(float4*)(ae + (size_t)i * 12 + l * 4) = make_float4(o[0], o[1], o[2], o[3]);
  }
}

// self-loop a_e = mean of incoming a_e via CSR gather (no atomics)
__global__ void k_loopae(const float* __restrict__ ae, const int* __restrict__ rowptr,
                         const int* __restrict__ csr, float* __restrict__ aeL, int n) {
  int v = blockIdx.x * 256 + threadIdx.x;
  if (v >= n) return;
  int beg = rowptr[v], end = rowptr[v + 1];
  float4 s0 = make_float4(0.f, 0.f, 0.f, 0.f);
  float4 s1 = make_float4(0.f, 0.f, 0.f, 0.f);
  float4 s2 = make_float4(0.f, 0.f, 0.f, 0.f);
  for (int j = beg; j < end; j++) {
    int eid = csr[j];
    const float4* p = (const float4*)(ae + (size_t)eid * 12);
    float4 a = p[0], b = p[1], c = p[2];
    s0.x += a.x; s0.y += a.y; s0.z += a.z; s0.w += a.w;
    s1.x += b.x; s1.y += b.y; s1.z += b.z; s1.w += b.w;
    s2.x += c.x; s2.y += c.y; s2.z += c.z; s2.w += c.w;
  }
  float inv = (end > beg) ? 1.f / (float)(end - beg) : 0.f;
  float4* o = (float4*)(aeL + (size_t)v * 12);
  o[0] = make_float4(s0.x * inv, s0.y * inv, s0.z * inv, s0.w * inv);
  o[1] = make_float4(s1.x * inv, s1.y * inv, s1.z * inv, s1.w * inv);
  o[2] = make_float4(s2.x * inv, s2.y * inv, s2.z * inv, s2.w * inv);
}

// ---------------- CSR build: exclusive scan of cnt -> rowptr, then fill ----------------
__global__ void k_scan1(const int* __restrict__ cnt, int* __restrict__ excl,
                        int* __restrict__ bsum, int n) {
  __shared__ int sh[256];
  int t = threadIdx.x;
  int i = blockIdx.x * 256 + t;
  int v = (i < n) ? cnt[i] : 0;
  sh[t] = v;
  __syncthreads();
  for (int off = 1; off < 256; off <<= 1) {
    int add = (t >= off) ? sh[t - off] : 0;
    __syncthreads();
    sh[t] += add;
    __syncthreads();
  }
  if (i < n) excl[i] = sh[t] - v;
  if (t == 255) bsum[blockIdx.x] = sh[255];
}

__global__ void k_scan2(int* __restrict__ bsum, int nb) {
  __shared__ int sh[512];
  int t = threadIdx.x;
  int v = (t < nb) ? bsum[t] : 0;
  sh[t] = v;
  __syncthreads();
  for (int off = 1; off < 512; off <<= 1) {
    int add = (t >= off) ? sh[t - off] : 0;
    __syncthreads();
    sh[t] += add;
    __syncthreads();
  }
  if (t < nb) bsum[t] = sh[t] - v;
}

__global__ void k_scan3(int* __restrict__ rowptr, const int* __restrict__ boff,
                        int* __restrict__ cursor, int n, int E) {
  int i = blockIdx.x * 256 + threadIdx.x;
  if (i < n) {
    int val = rowptr[i] + boff[i >> 8];
    rowptr[i] = val;
    cursor[i] = val;
  }
  if (i == 0) rowptr[n] = E;
}

__global__ void k_fill(const int* __restrict__ dst, int* __restrict__ cursor,
                       int* __restrict__ csr, int E) {
  int i = blockIdx.x * 256 + threadIdx.x;
  if (i >= E) return;
  int pos = atomicAdd(&cursor[dst[i]], 1);
  csr[pos] = i;
}

// ---------------- x = h @ gat_lin[l]  (col-half per block.y, 32 rows/iter) ----------------
__global__ void k_x(const float* __restrict__ h, const float* __restrict__ L_g,
                    float* __restrict__ x, int n) {
  __shared__ float L[128 * 64];
  __shared__ float hr[32][128];
  int t = threadIdx.x;  // 256
  int ch = blockIdx.y;  // col half 0/1
  for (int i = t; i < 128 * 64; i += 256) {
    int k = i >> 6, c = i & 63;
    L[i] = L_g[k * 128 + ch * 64 + c];
  }
  __syncthreads();
  int col = t & 63;
  int rb = (t >> 6) * 8;  // 0,8,16,24
  for (int base = blockIdx.x * 32; base < n; base += gridDim.x * 32) {
    int nr = min(32, n - base);
    for (int i = t; i < nr * 128; i += 256) hr[i >> 7][i & 127] = h[(size_t)base * 128 + i];
    __syncthreads();
    float acc[8] = {0.f, 0.f, 0.f, 0.f, 0.f, 0.f, 0.f, 0.f};
    for (int k = 0; k < 128; k++) {
      float w = L[k * 64 + col];
#pragma unroll
      for (int r = 0; r < 8; r++) acc[r] += hr[rb + r][k] * w;
    }
#pragma unroll
    for (int r = 0; r < 8; r++) {
      int v = base + rb + r;
      if (v < n) x[(size_t)v * 128 + ch * 64 + col] = acc[r];
    }
    __syncthreads();
  }
}

// ---------------- a_s, a_d: per-head dot of x row with att vectors ----------------
__global__ void k_att(const float* __restrict__ x, const float* __restrict__ att_s,
                      const float* __restrict__ att_d, float* __restrict__ a_s,
                      float* __restrict__ a_d, int n) {
  int t = threadIdx.x;  // 256
  int j = t & 127;
  float asv = att_s[j];
  float adv = att_d[j];
  int half = t >> 7;
  for (int vb = blockIdx.x * 2; vb < n; vb += gridDim.x * 2) {
    int v = vb + half;
    if (v < n) {
      float xv = x[(size_t)v * 128 + j];
      float ps = xv * asv, pd = xv * adv;
#pragma unroll
      for (int m = 16; m >= 1; m >>= 1) {
        ps += __shfl_xor(ps, m);
        pd += __shfl_xor(pd, m);
      }
      if ((j & 31) == 0) {
        a_s[(size_t)v * 4 + (j >> 5)] = ps;
        a_d[(size_t)v * 4 + (j >> 5)] = pd;
      }
    }
  }
}

// -------- per-dst online softmax + weighted gather; one wave per node; h updated in place --------
__global__ void k_agg(const float* __restrict__ x, const float* __restrict__ a_s,
                      const float* __restrict__ a_d, const float* __restrict__ ae,
                      const float* __restrict__ ae_loop,
                      const int* __restrict__ rowptr, const int* __restrict__ csr,
                      const int* __restrict__ srcarr, const float* __restrict__ bias,
                      float* __restrict__ hout, int n, int l) {
  int wid = threadIdx.x >> 6;
  int v = blockIdx.x * 4 + wid;
  if (v >= n) return;
  int lane = threadIdx.x & 63;
  float4 ad = *(const float4*)(a_d + (size_t)v * 4);
  float4 aeL = *(const float4*)(ae_loop + (size_t)v * 12 + l * 4);
  float4 asv = *(const float4*)(a_s + (size_t)v * 4);
  float m0 = leaky02(asv.x + ad.x + aeL.x);
  float m1 = leaky02(asv.y + ad.y + aeL.y);
  float m2 = leaky02(asv.z + ad.z + aeL.z);
  float m3 = leaky02(asv.w + ad.w + aeL.w);
  float s0 = 1.f, s1 = 1.f, s2 = 1.f, s3 = 1.f;
  float acc0 = x[(size_t)v * HID + lane];
  float acc1 = x[(size_t)v * HID + 64 + lane];
  int beg = rowptr[v], end = rowptr[v + 1];
  bool hi = (lane & 32) != 0;
  for (int j = beg; j < end; j++) {
    int eid = csr[j];
    int src = srcarr[eid];
    float4 aev = *(const float4*)(ae + (size_t)eid * 12 + l * 4);
    float4 asrc = *(const float4*)(a_s + (size_t)src * 4);
    float l0 = leaky02(asrc.x + ad.x + aev.x);
    float l1 = leaky02(asrc.y + ad.y + aev.y);
    float l2 = leaky02(asrc.z + ad.z + aev.z);
    float l3 = leaky02(asrc.w + ad.w + aev.w);
    float x0 = x[(size_t)src * HID + lane];
    float x1 = x[(size_t)src * HID + 64 + lane];
    float n0 = fmaxf(m0, l0), n1 = fmaxf(m1, l1), n2 = fmaxf(m2, l2), n3 = fmaxf(m3, l3);
    float c0 = __expf(m0 - n0), c1 = __expf(m1 - n1), c2 = __expf(m2 - n2), c3 = __expf(m3 - n3);
    float p0 = __expf(l0 - n0), p1 = __expf(l1 - n1), p2 = __expf(l2 - n2), p3 = __expf(l3 - n3);
    s0 = s0 * c0 + p0; s1 = s1 * c1 + p1; s2 = s2 * c2 + p2; s3 = s3 * c3 + p3;
    m0 = n0; m1 = n1; m2 = n2; m3 = n3;
    float cA = hi ? c1 : c0, pA = hi ? p1 : p0;
    float cB = hi ? c3 : c2, pB = hi ? p3 : p2;
    acc0 = acc0 * cA + pA * x0;
    acc1 = acc1 * cB + pB * x1;
  }
  float sA = hi ? s1 : s0;
  float sB = hi ? s3 : s2;
  float r0 = acc0 / sA + bias[l * HID + lane];
  float r1 = acc1 / sB + bias[l * HID + 64 + lane];
  hout[(size_t)v * HID + lane] = fmaxf(r0, 0.f);
  hout[(size_t)v * HID + 64 + lane] = fmaxf(r1, 0.f);
}

// ---------------- pooling: batch is sorted -> register accumulate, flush on change ----------------
__global__ void k_pool(const float* __restrict__ h, const int* __restrict__ batch,
                       float* __restrict__ g, int n) {
  int t = threadIdx.x;  // 128
  int per = (n + gridDim.x - 1) / gridDim.x;
  int start = blockIdx.x * per;
  int end = min(n, start + per);
  float acc = 0.f;
  int cur = -1;
  for (int v = start; v < end; v++) {
    int b = batch[v];
    if (b != cur) {
      if (cur >= 0) atomicAdd(&g[cur * 128 + t], acc);
      acc = 0.f;
      cur = b;
    }
    acc += h[(size_t)v * 128 + t];
  }
  if (cur >= 0) atomicAdd(&g[cur * 128 + t], acc);
}

// ---------------- head MLP on pooled g (8x128) ----------------
__global__ void k_head(const float* __restrict__ g, const float* __restrict__ Wr1,
                       const float* __restrict__ br1, const float* __restrict__ Wr2,
                       const float* __restrict__ br2, float* __restrict__ out, int G_) {
  __shared__ float gl[8 * 128];
  __shared__ float red[128];
  int t = threadIdx.x;  // 128
  for (int i = t; i < G_ * 128; i += 128) gl[i] = g[i];
  __syncthreads();
  for (int i = 0; i < G_; i++) {
    float acc = br1[t];
    for (int k = 0; k < 128; k++) acc += gl[i * 128 + k] * Wr1[k * 128 + t];
    float hv = fmaxf(acc, 0.f);
    red[t] = hv * Wr2[t];
    __syncthreads();
    if (t == 0) {
      float s = br2[0];
      for (int k = 0; k < 128; k++) s += red[k];
      out[i] = s;
    }
    __syncthreads();
  }
}

extern "C" void kernel_launch(void* const* d_in, const int* in_sizes, int n_in,
                              void* d_out, int out_size, void* d_ws, size_t ws_size,
                              hipStream_t stream) {
  const float* node_numeric = (const float*)d_in[0];
  const int* node_cat0 = (const int*)d_in[1];
  const int* node_cat1 = (const int*)d_in[2];
  const float* edge_numeric = (const float*)d_in[3];
  const int* edge_cat0 = (const int*)d_in[4];
  const int* edge_cat1 = (const int*)d_in[5];
  const int* edge_index = (const int*)d_in[6];
  const int* batch = (const int*)d_in[7];
  const float* recipe = (const float*)d_in[8];
  const float* emb_node0 = (const float*)d_in[9];
  const float* emb_node1 = (const float*)d_in[10];
  const float* emb_edge0 = (const float*)d_in[11];
  const float* emb_edge1 = (const float*)d_in[12];
  const float* W_in = (const float*)d_in[13];
  const float* b_in = (const float*)d_in[14];
  const float* W_edge = (const float*)d_in[15];
  const float* b_edge = (const float*)d_in[16];
  const float* gat_lin = (const float*)d_in[17];
  const float* gat_lin_edge = (const float*)d_in[18];
  const float* att_src = (const float*)d_in[19];
  const float* att_dst = (const float*)d_in[20];
  const float* att_edge = (const float*)d_in[21];
  const float* gat_bias = (const float*)d_in[22];
  const float* W_r1 = (const float*)d_in[23];
  const float* b_r1 = (const float*)d_in[24];
  const float* W_r2 = (const float*)d_in[25];
  const float* b_r2 = (const float*)d_in[26];

  int N = in_sizes[0] / 8;
  int E = in_sizes[3] / 4;
  int Gn = in_sizes[8] / 16;
  const int* srcArr = edge_index;
  const int* dstArr = edge_index + E;

  char* ws = (char*)d_ws;
  size_t o = 0;
  auto alloc = [&](size_t b) {
    char* p = ws + o;
    o = (o + b + 255) & ~(size_t)255;
    return p;
  };
  float* h = (float*)alloc((size_t)N * 128 * 4);
  float* x = (float*)alloc((size_t)N * 128 * 4);
  float* ae = (float*)alloc((size_t)E * 12 * 4);
  float* aeL = (float*)alloc((size_t)N * 12 * 4);
  float* a_s = (float*)alloc((size_t)N * 4 * 4);
  float* a_d = (float*)alloc((size_t)N * 4 * 4);
  float* P = (float*)alloc(216 * 4);
  float* q = (float*)alloc(12 * 4);
  int* cnt = (int*)alloc((size_t)N * 4);
  int* rowptr = (int*)alloc((size_t)(N + 1) * 4);
  int* cursor = (int*)alloc((size_t)N * 4);
  int* bsum = (int*)alloc(512 * 4);
  int* csr = (int*)alloc((size_t)E * 4);
  float* g = (float*)alloc((size_t)Gn * 128 * 4);
  (void)ws_size;

  (void)hipMemsetAsync(cnt, 0, (size_t)N * 4, stream);
  (void)hipMemsetAsync(g, 0, (size_t)Gn * 128 * 4, stream);

  int nbl = (N + 255) / 256;
  int ebl = (E + 255) / 256;

  k_enc<<<512, 256, 0, stream>>>(node_numeric, node_cat0, node_cat1, batch, recipe,
                                 emb_node0, emb_node1, W_in, b_in, h, N);
  k_prep<<<1, 128, 0, stream>>>(gat_lin_edge, att_edge, W_edge, b_edge, P, q);
  k_deg<<<ebl, 256, 0, stream>>>(dstArr, cnt, E);
  k_ae<<<ebl, 256, 0, stream>>>(edge_numeric, edge_cat0, edge_cat1,
                                emb_edge0, emb_edge1, P, q, ae, E);
  k_scan1<<<nbl, 256, 0, stream>>>(cnt, rowptr, bsum, N);
  k_scan2<<<1, 512, 0, stream>>>(bsum, nbl);
  k_scan3<<<nbl, 256, 0, stream>>>(rowptr, bsum, cursor, N, E);
  k_fill<<<ebl, 256, 0, stream>>>(dstArr, cursor, csr, E);
  k_loopae<<<nbl, 256, 0, stream>>>(ae, rowptr, csr, aeL, N);

  for (int l = 0; l < 3; l++) {
    dim3 gx(512, 2);
    k_x<<<gx, 256, 0, stream>>>(h, gat_lin + l * 16384, x, N);
    k_att<<<1024, 256, 0, stream>>>(x, att_src + l * 128, att_dst + l * 128, a_s, a_d, N);
    k_agg<<<(N + 3) / 4, 256, 0, stream>>>(x, a_s, a_d, ae, aeL, rowptr, csr, srcArr,
                                           gat_bias, h, N, l);
  }
  k_pool<<<512, 128, 0, stream>>>(h, batch, g, N);
  k_head<<<1, 128, 0, stream>>>(g, W_r1, b_r1, W_r2, b_r2, (float*)d_out, Gn);
}

// Round 4
// 1105.983 us; speedup vs baseline: 1.4696x; 1.1587x over previous
//
#include <hip/hip_runtime.h>
#include <math.h>

#define HID 128

__device__ __forceinline__ float leaky02(float z) { return z >= 0.f ? z : 0.2f * z; }

// ---------------- node encoder: h = relu(concat(feat) @ W_in + b_in) ----------------
// No LDS, no barriers. 256 threads = 2 nodes (128 cols each); per-node loads are
// wave-uniform -> 1 transaction each. W column kept in registers (38 VGPR).
__global__ void k_enc(const float* __restrict__ nodenum, const int* __restrict__ c0,
                      const int* __restrict__ c1, const int* __restrict__ batch,
                      const float* __restrict__ recipe,
                      const float* __restrict__ e0, const float* __restrict__ e1,
                      const float* __restrict__ Win, const float* __restrict__ bin,
                      float* __restrict__ h, int n) {
  int t = threadIdx.x;  // 256
  int col = t & 127;
  int sub = t >> 7;  // 0/1: which node of the pair
  float w[38];
#pragma unroll
  for (int k = 0; k < 38; k++) w[k] = Win[k * 128 + col];
  float bias = bin[col];
  for (int v = blockIdx.x * 2 + sub; v < n; v += gridDim.x * 2) {
    float f[38];
    const float4* nm = (const float4*)(nodenum + (size_t)v * 8);
    float4 n0 = nm[0], n1 = nm[1];
    f[0] = n0.x; f[1] = n0.y; f[2] = n0.z; f[3] = n0.w;
    f[4] = n1.x; f[5] = n1.y; f[6] = n1.z; f[7] = n1.w;
    int a0 = c0[v], a1 = c1[v], b = batch[v];
    const float2* p0 = (const float2*)(e0 + a0 * 6);
    float2 q0 = p0[0], q1 = p0[1], q2 = p0[2];
    f[8] = q0.x; f[9] = q0.y; f[10] = q1.x; f[11] = q1.y; f[12] = q2.x; f[13] = q2.y;
    const float4* p1 = (const float4*)(e1 + a1 * 8);
    float4 r0 = p1[0], r1 = p1[1];
    f[14] = r0.x; f[15] = r0.y; f[16] = r0.z; f[17] = r0.w;
    f[18] = r1.x; f[19] = r1.y; f[20] = r1.z; f[21] = r1.w;
    const float4* pr = (const float4*)(recipe + b * 16);
    float4 c4;
    c4 = pr[0]; f[22] = c4.x; f[23] = c4.y; f[24] = c4.z; f[25] = c4.w;
    c4 = pr[1]; f[26] = c4.x; f[27] = c4.y; f[28] = c4.z; f[29] = c4.w;
    c4 = pr[2]; f[30] = c4.x; f[31] = c4.y; f[32] = c4.z; f[33] = c4.w;
    c4 = pr[3]; f[34] = c4.x; f[35] = c4.y; f[36] = c4.z; f[37] = c4.w;
    float acc = bias;
#pragma unroll
    for (int k = 0; k < 38; k++) acc += f[k] * w[k];
    h[(size_t)v * 128 + col] = fmaxf(acc, 0.f);
  }
}

// ---------------- precompute P_l (18x4), q_l (4): a_e = raw @ P + q ----------------
__global__ void k_prep(const float* __restrict__ gle, const float* __restrict__ atte,
                       const float* __restrict__ We, const float* __restrict__ be,
                       float* __restrict__ P, float* __restrict__ q) {
  __shared__ float M[128 * 4];
  int t = threadIdx.x;  // 128
  for (int l = 0; l < 3; l++) {
    {
      int k = t;
#pragma unroll
      for (int hh = 0; hh < 4; hh++) {
        float acc = 0.f;
        for (int c = 0; c < 32; c++)
          acc += gle[l * 16384 + k * 128 + hh * 32 + c] * atte[l * 128 + hh * 32 + c];
        M[k * 4 + hh] = acc;
      }
    }
    __syncthreads();
    if (t < 72) {
      int j = t >> 2, hh = t & 3;
      float acc = 0.f;
      for (int k = 0; k < 128; k++) acc += We[j * 128 + k] * M[k * 4 + hh];
      P[(l * 18 + j) * 4 + hh] = acc;
    }
    if (t < 4) {
      float acc = 0.f;
      for (int k = 0; k < 128; k++) acc += be[k] * M[k * 4 + t];
      q[l * 4 + t] = acc;
    }
    __syncthreads();
  }
}

// ---------------- degree histogram (int atomics only) ----------------
__global__ void k_deg(const int* __restrict__ dst, int* __restrict__ cnt, int E) {
  int i = blockIdx.x * 256 + threadIdx.x;
  if (i < E) atomicAdd(&cnt[dst[i]], 1);
}

// ------- per-edge a_e for all 3 layers (pure streaming, no atomics) -------
__global__ void k_ae(const float* __restrict__ enum_, const int* __restrict__ ec0,
                     const int* __restrict__ ec1,
                     const float* __restrict__ ee0, const float* __restrict__ ee1,
                     const float* __restrict__ P, const float* __restrict__ q,
                     float* __restrict__ ae, int E) {
  __shared__ float Ps[216];
  __shared__ float qs[12];
  int t = threadIdx.x;
  for (int i = t; i < 216; i += 256) Ps[i] = P[i];
  if (t < 12) qs[t] = q[t];
  __syncthreads();
  int i = blockIdx.x * 256 + t;
  if (i >= E) return;
  float raw[18];
  float4 nm = *(const float4*)(enum_ + (size_t)i * 4);
  raw[0] = nm.x; raw[1] = nm.y; raw[2] = nm.z; raw[3] = nm.w;
  int a0 = ec0[i], a1 = ec1[i];
  float4 eb0 = *(const float4*)(ee0 + a0 * 4);
  raw[4] = eb0.x; raw[5] = eb0.y; raw[6] = eb0.z; raw[7] = eb0.w;
#pragma unroll
  for (int j = 0; j < 10; j++) raw[8 + j] = ee1[a1 * 10 + j];
#pragma unroll
  for (int l = 0; l < 3; l++) {
    float o[4];
#pragma unroll
    for (int hh = 0; hh < 4; hh++) {
      float acc = qs[l * 4 + hh];
#pragma unroll
      for (int j = 0; j < 18; j++) acc += raw[j] * Ps[(l * 18 + j) * 4 + hh];
      o[hh] = acc;
    }
    *(float4*)(ae + (size_t)i * 12 + l * 4) = make_float4(o[0], o[1], o[2], o[3]);
  }
}

// self-loop a_e = mean of incoming a_e via CSR gather (no atomics)
__global__ void k_loopae(const float* __restrict__ ae, const int* __restrict__ rowptr,
                         const int* __restrict__ csr, float* __restrict__ aeL, int n) {
  int v = blockIdx.x * 256 + threadIdx.x;
  if (v >= n) return;
  int beg = rowptr[v], end = rowptr[v + 1];
  float4 s0 = make_float4(0.f, 0.f, 0.f, 0.f);
  float4 s1 = make_float4(0.f, 0.f, 0.f, 0.f);
  float4 s2 = make_float4(0.f, 0.f, 0.f, 0.f);
  for (int j = beg; j < end; j++) {
    int eid = csr[j];
    const float4* p = (const float4*)(ae + (size_t)eid * 12);
    float4 a = p[0], b = p[1], c = p[2];
    s0.x += a.x; s0.y += a.y; s0.z += a.z; s0.w += a.w;
    s1.x += b.x; s1.y += b.y; s1.z += b.z; s1.w += b.w;
    s2.x += c.x; s2.y += c.y; s2.z += c.z; s2.w += c.w;
  }
  float inv = (end > beg) ? 1.f / (float)(end - beg) : 0.f;
  float4* o = (float4*)(aeL + (size_t)v * 12);
  o[0] = make_float4(s0.x * inv, s0.y * inv, s0.z * inv, s0.w * inv);
  o[1] = make_float4(s1.x * inv, s1.y * inv, s1.z * inv, s1.w * inv);
  o[2] = make_float4(s2.x * inv, s2.y * inv, s2.z * inv, s2.w * inv);
}

// ---------------- CSR build: exclusive scan of cnt -> rowptr, then fill ----------------
__global__ void k_scan1(const int* __restrict__ cnt, int* __restrict__ excl,
                        int* __restrict__ bsum, int n) {
  __shared__ int sh[256];
  int t = threadIdx.x;
  int i = blockIdx.x * 256 + t;
  int v = (i < n) ? cnt[i] : 0;
  sh[t] = v;
  __syncthreads();
  for (int off = 1; off < 256; off <<= 1) {
    int add = (t >= off) ? sh[t - off] : 0;
    __syncthreads();
    sh[t] += add;
    __syncthreads();
  }
  if (i < n) excl[i] = sh[t] - v;
  if (t == 255) bsum[blockIdx.x] = sh[255];
}

__global__ void k_scan2(int* __restrict__ bsum, int nb) {
  __shared__ int sh[512];
  int t = threadIdx.x;
  int v = (t < nb) ? bsum[t] : 0;
  sh[t] = v;
  __syncthreads();
  for (int off = 1; off < 512; off <<= 1) {
    int add = (t >= off) ? sh[t - off] : 0;
    __syncthreads();
    sh[t] += add;
    __syncthreads();
  }
  if (t < nb) bsum[t] = sh[t] - v;
}

__global__ void k_scan3(int* __restrict__ rowptr, const int* __restrict__ boff,
                        int* __restrict__ cursor, int n, int E) {
  int i = blockIdx.x * 256 + threadIdx.x;
  if (i < n) {
    int val = rowptr[i] + boff[i >> 8];
    rowptr[i] = val;
    cursor[i] = val;
  }
  if (i == 0) rowptr[n] = E;
}

__global__ void k_fill(const int* __restrict__ dst, int* __restrict__ cursor,
                       int* __restrict__ csr, int E) {
  int i = blockIdx.x * 256 + threadIdx.x;
  if (i >= E) return;
  int pos = atomicAdd(&cursor[dst[i]], 1);
  csr[pos] = i;
}

// ------- x = h @ gat_lin[l] (col-half per block.y, 32 rows/iter) + fused a_s/a_d -------
__global__ void k_x(const float* __restrict__ h, const float* __restrict__ L_g,
                    const float* __restrict__ att_s, const float* __restrict__ att_d,
                    float* __restrict__ x, float* __restrict__ a_s,
                    float* __restrict__ a_d, int n) {
  __shared__ float L[128 * 64];
  __shared__ float hr[32][128];
  int t = threadIdx.x;  // 256
  int ch = blockIdx.y;  // col half 0/1
  for (int i = t; i < 128 * 64; i += 256) {
    int k = i >> 6, c = i & 63;
    L[i] = L_g[k * 128 + ch * 64 + c];
  }
  int col = t & 63;
  int rb = (t >> 6) * 8;  // 0,8,16,24
  int gcol = ch * 64 + col;
  float av_s = att_s[gcol];
  float av_d = att_d[gcol];
  int head = gcol >> 5;
  __syncthreads();
  for (int base = blockIdx.x * 32; base < n; base += gridDim.x * 32) {
    int nr = min(32, n - base);
    for (int i = t; i < nr * 128; i += 256) hr[i >> 7][i & 127] = h[(size_t)base * 128 + i];
    __syncthreads();
    float acc[8] = {0.f, 0.f, 0.f, 0.f, 0.f, 0.f, 0.f, 0.f};
    for (int k = 0; k < 128; k++) {
      float w = L[k * 64 + col];
#pragma unroll
      for (int r = 0; r < 8; r++) acc[r] += hr[rb + r][k] * w;
    }
#pragma unroll
    for (int r = 0; r < 8; r++) {
      int v = base + rb + r;
      if (v < n) x[(size_t)v * 128 + gcol] = acc[r];
    }
    // fused per-head attention dots: reduce acc[r]*att over the 32 cols of this head
    // (lanes 0-31 = head 2ch, lanes 32-63 = head 2ch+1; xor<=16 stays in-half)
#pragma unroll
    for (int r = 0; r < 8; r++) {
      float ps = acc[r] * av_s;
      float pd = acc[r] * av_d;
#pragma unroll
      for (int m = 16; m >= 1; m >>= 1) {
        ps += __shfl_xor(ps, m);
        pd += __shfl_xor(pd, m);
      }
      if ((col & 31) == 0) {
        int v = base + rb + r;
        if (v < n) {
          a_s[(size_t)v * 4 + head] = ps;
          a_d[(size_t)v * 4 + head] = pd;
        }
      }
    }
    __syncthreads();
  }
}

// -------- per-dst online softmax + weighted gather; one wave per node; h updated in place --------
__global__ void k_agg(const float* __restrict__ x, const float* __restrict__ a_s,
                      const float* __restrict__ a_d, const float* __restrict__ ae,
                      const float* __restrict__ ae_loop,
                      const int* __restrict__ rowptr, const int* __restrict__ csr,
                      const int* __restrict__ srcarr, const float* __restrict__ bias,
                      float* __restrict__ hout, int n, int l) {
  int wid = threadIdx.x >> 6;
  int v = blockIdx.x * 4 + wid;
  if (v >= n) return;
  int lane = threadIdx.x & 63;
  float4 ad = *(const float4*)(a_d + (size_t)v * 4);
  float4 aeL = *(const float4*)(ae_loop + (size_t)v * 12 + l * 4);
  float4 asv = *(const float4*)(a_s + (size_t)v * 4);
  float m0 = leaky02(asv.x + ad.x + aeL.x);
  float m1 = leaky02(asv.y + ad.y + aeL.y);
  float m2 = leaky02(asv.z + ad.z + aeL.z);
  float m3 = leaky02(asv.w + ad.w + aeL.w);
  float s0 = 1.f, s1 = 1.f, s2 = 1.f, s3 = 1.f;
  float acc0 = x[(size_t)v * HID + lane];
  float acc1 = x[(size_t)v * HID + 64 + lane];
  int beg = rowptr[v], end = rowptr[v + 1];
  bool hi = (lane & 32) != 0;
  for (int j = beg; j < end; j++) {
    int eid = csr[j];
    int src = srcarr[eid];
    float4 aev = *(const float4*)(ae + (size_t)eid * 12 + l * 4);
    float4 asrc = *(const float4*)(a_s + (size_t)src * 4);
    float l0 = leaky02(asrc.x + ad.x + aev.x);
    float l1 = leaky02(asrc.y + ad.y + aev.y);
    float l2 = leaky02(asrc.z + ad.z + aev.z);
    float l3 = leaky02(asrc.w + ad.w + aev.w);
    float x0 = x[(size_t)src * HID + lane];
    float x1 = x[(size_t)src * HID + 64 + lane];
    float n0 = fmaxf(m0, l0), n1 = fmaxf(m1, l1), n2 = fmaxf(m2, l2), n3 = fmaxf(m3, l3);
    float c0 = __expf(m0 - n0), c1 = __expf(m1 - n1), c2 = __expf(m2 - n2), c3 = __expf(m3 - n3);
    float p0 = __expf(l0 - n0), p1 = __expf(l1 - n1), p2 = __expf(l2 - n2), p3 = __expf(l3 - n3);
    s0 = s0 * c0 + p0; s1 = s1 * c1 + p1; s2 = s2 * c2 + p2; s3 = s3 * c3 + p3;
    m0 = n0; m1 = n1; m2 = n2; m3 = n3;
    float cA = hi ? c1 : c0, pA = hi ? p1 : p0;
    float cB = hi ? c3 : c2, pB = hi ? p3 : p2;
    acc0 = acc0 * cA + pA * x0;
    acc1 = acc1 * cB + pB * x1;
  }
  float sA = hi ? s1 : s0;
  float sB = hi ? s3 : s2;
  float r0 = acc0 / sA + bias[l * HID + lane];
  float r1 = acc1 / sB + bias[l * HID + 64 + lane];
  hout[(size_t)v * HID + lane] = fmaxf(r0, 0.f);
  hout[(size_t)v * HID + 64 + lane] = fmaxf(r1, 0.f);
}

// ---------------- pooling: batch is sorted -> register accumulate, flush on change ----------------
__global__ void k_pool(const float* __restrict__ h, const int* __restrict__ batch,
                       float* __restrict__ g, int n) {
  int t = threadIdx.x;  // 128
  int per = (n + gridDim.x - 1) / gridDim.x;
  int start = blockIdx.x * per;
  int end = min(n, start + per);
  float acc = 0.f;
  int cur = -1;
  for (int v = start; v < end; v++) {
    int b = batch[v];
    if (b != cur) {
      if (cur >= 0) atomicAdd(&g[cur * 128 + t], acc);
      acc = 0.f;
      cur = b;
    }
    acc += h[(size_t)v * 128 + t];
  }
  if (cur >= 0) atomicAdd(&g[cur * 128 + t], acc);
}

// ---------------- head MLP on pooled g (8x128) ----------------
__global__ void k_head(const float* __restrict__ g, const float* __restrict__ Wr1,
                       const float* __restrict__ br1, const float* __restrict__ Wr2,
                       const float* __restrict__ br2, float* __restrict__ out, int G_) {
  __shared__ float gl[8 * 128];
  __shared__ float red[128];
  int t = threadIdx.x;  // 128
  for (int i = t; i < G_ * 128; i += 128) gl[i] = g[i];
  __syncthreads();
  for (int i = 0; i < G_; i++) {
    float acc = br1[t];
    for (int k = 0; k < 128; k++) acc += gl[i * 128 + k] * Wr1[k * 128 + t];
    float hv = fmaxf(acc, 0.f);
    red[t] = hv * Wr2[t];
    __syncthreads();
    if (t == 0) {
      float s = br2[0];
      for (int k = 0; k < 128; k++) s += red[k];
      out[i] = s;
    }
    __syncthreads();
  }
}

extern "C" void kernel_launch(void* const* d_in, const int* in_sizes, int n_in,
                              void* d_out, int out_size, void* d_ws, size_t ws_size,
                              hipStream_t stream) {
  const float* node_numeric = (const float*)d_in[0];
  const int* node_cat0 = (const int*)d_in[1];
  const int* node_cat1 = (const int*)d_in[2];
  const float* edge_numeric = (const float*)d_in[3];
  const int* edge_cat0 = (const int*)d_in[4];
  const int* edge_cat1 = (const int*)d_in[5];
  const int* edge_index = (const int*)d_in[6];
  const int* batch = (const int*)d_in[7];
  const float* recipe = (const float*)d_in[8];
  const float* emb_node0 = (const float*)d_in[9];
  const float* emb_node1 = (const float*)d_in[10];
  const float* emb_edge0 = (const float*)d_in[11];
  const float* emb_edge1 = (const float*)d_in[12];
  const float* W_in = (const float*)d_in[13];
  const float* b_in = (const float*)d_in[14];
  const float* W_edge = (const float*)d_in[15];
  const float* b_edge = (const float*)d_in[16];
  const float* gat_lin = (const float*)d_in[17];
  const float* gat_lin_edge = (const float*)d_in[18];
  const float* att_src = (const float*)d_in[19];
  const float* att_dst = (const float*)d_in[20];
  const float* att_edge = (const float*)d_in[21];
  const float* gat_bias = (const float*)d_in[22];
  const float* W_r1 = (const float*)d_in[23];
  const float* b_r1 = (const float*)d_in[24];
  const float* W_r2 = (const float*)d_in[25];
  const float* b_r2 = (const float*)d_in[26];

  int N = in_sizes[0] / 8;
  int E = in_sizes[3] / 4;
  int Gn = in_sizes[8] / 16;
  const int* srcArr = edge_index;
  const int* dstArr = edge_index + E;

  char* ws = (char*)d_ws;
  size_t o = 0;
  auto alloc = [&](size_t b) {
    char* p = ws + o;
    o = (o + b + 255) & ~(size_t)255;
    return p;
  };
  float* h = (float*)alloc((size_t)N * 128 * 4);
  float* x = (float*)alloc((size_t)N * 128 * 4);
  float* ae = (float*)alloc((size_t)E * 12 * 4);
  float* aeL = (float*)alloc((size_t)N * 12 * 4);
  float* a_s = (float*)alloc((size_t)N * 4 * 4);
  float* a_d = (float*)alloc((size_t)N * 4 * 4);
  float* P = (float*)alloc(216 * 4);
  float* q = (float*)alloc(12 * 4);
  int* cnt = (int*)alloc((size_t)N * 4);
  int* rowptr = (int*)alloc((size_t)(N + 1) * 4);
  int* cursor = (int*)alloc((size_t)N * 4);
  int* bsum = (int*)alloc(512 * 4);
  int* csr = (int*)alloc((size_t)E * 4);
  float* g = (float*)alloc((size_t)Gn * 128 * 4);
  (void)ws_size;

  (void)hipMemsetAsync(cnt, 0, (size_t)N * 4, stream);
  (void)hipMemsetAsync(g, 0, (size_t)Gn * 128 * 4, stream);

  int nbl = (N + 255) / 256;
  int ebl = (E + 255) / 256;

  k_enc<<<2048, 256, 0, stream>>>(node_numeric, node_cat0, node_cat1, batch, recipe,
                                  emb_node0, emb_node1, W_in, b_in, h, N);
  k_prep<<<1, 128, 0, stream>>>(gat_lin_edge, att_edge, W_edge, b_edge, P, q);
  k_deg<<<ebl, 256, 0, stream>>>(dstArr, cnt, E);
  k_ae<<<ebl, 256, 0, stream>>>(edge_numeric, edge_cat0, edge_cat1,
                                emb_edge0, emb_edge1, P, q, ae, E);
  k_scan1<<<nbl, 256, 0, stream>>>(cnt, rowptr, bsum, N);
  k_scan2<<<1, 512, 0, stream>>>(bsum, nbl);
  k_scan3<<<nbl, 256, 0, stream>>>(rowptr, bsum, cursor, N, E);
  k_fill<<<ebl, 256, 0, stream>>>(dstArr, cursor, csr, E);
  k_loopae<<<nbl, 256, 0, stream>>>(ae, rowptr, csr, aeL, N);

  for (int l = 0; l < 3; l++) {
    dim3 gx(512, 2);
    k_x<<<gx, 256, 0, stream>>>(h, gat_lin + l * 16384, att_src + l * 128,
                                att_dst + l * 128, x, a_s, a_d, N);
    k_agg<<<(N + 3) / 4, 256, 0, stream>>>(x, a_s, a_d, ae, aeL, rowptr, csr, srcArr,
                                           gat_bias, h, N, l);
  }
  k_pool<<<512, 128, 0, stream>>>(h, batch, g, N);
  k_head<<<1, 128, 0, stream>>>(g, W_r1, b_r1, W_r2, b_r2, (float*)d_out, Gn);
}

// Round 5
// 940.116 us; speedup vs baseline: 1.7289x; 1.1764x over previous
//
#include <hip/hip_runtime.h>
#include <math.h>

#define HID 128
#define XTP 132  // padded LDS stride (floats): 132%32=4 -> 2-way conflicts (free), float4-aligned

__device__ __forceinline__ float leaky02(float z) { return z >= 0.f ? z : 0.2f * z; }

// ---------------- node encoder: h = relu(concat(feat) @ W_in + b_in) ----------------
// No LDS, no barriers. 256 threads = 2 nodes (128 cols each); per-node loads are
// wave-uniform -> 1 transaction each. W column kept in registers (38 VGPR).
__global__ void k_enc(const float* __restrict__ nodenum, const int* __restrict__ c0,
                      const int* __restrict__ c1, const int* __restrict__ batch,
                      const float* __restrict__ recipe,
                      const float* __restrict__ e0, const float* __restrict__ e1,
                      const float* __restrict__ Win, const float* __restrict__ bin,
                      float* __restrict__ h, int n) {
  int t = threadIdx.x;  // 256
  int col = t & 127;
  int sub = t >> 7;  // 0/1: which node of the pair
  float w[38];
#pragma unroll
  for (int k = 0; k < 38; k++) w[k] = Win[k * 128 + col];
  float bias = bin[col];
  for (int v = blockIdx.x * 2 + sub; v < n; v += gridDim.x * 2) {
    float f[38];
    const float4* nm = (const float4*)(nodenum + (size_t)v * 8);
    float4 n0 = nm[0], n1 = nm[1];
    f[0] = n0.x; f[1] = n0.y; f[2] = n0.z; f[3] = n0.w;
    f[4] = n1.x; f[5] = n1.y; f[6] = n1.z; f[7] = n1.w;
    int a0 = c0[v], a1 = c1[v], b = batch[v];
    const float2* p0 = (const float2*)(e0 + a0 * 6);
    float2 q0 = p0[0], q1 = p0[1], q2 = p0[2];
    f[8] = q0.x; f[9] = q0.y; f[10] = q1.x; f[11] = q1.y; f[12] = q2.x; f[13] = q2.y;
    const float4* p1 = (const float4*)(e1 + a1 * 8);
    float4 r0 = p1[0], r1 = p1[1];
    f[14] = r0.x; f[15] = r0.y; f[16] = r0.z; f[17] = r0.w;
    f[18] = r1.x; f[19] = r1.y; f[20] = r1.z; f[21] = r1.w;
    const float4* pr = (const float4*)(recipe + b * 16);
    float4 c4;
    c4 = pr[0]; f[22] = c4.x; f[23] = c4.y; f[24] = c4.z; f[25] = c4.w;
    c4 = pr[1]; f[26] = c4.x; f[27] = c4.y; f[28] = c4.z; f[29] = c4.w;
    c4 = pr[2]; f[30] = c4.x; f[31] = c4.y; f[32] = c4.z; f[33] = c4.w;
    c4 = pr[3]; f[34] = c4.x; f[35] = c4.y; f[36] = c4.z; f[37] = c4.w;
    float acc = bias;
#pragma unroll
    for (int k = 0; k < 38; k++) acc += f[k] * w[k];
    h[(size_t)v * 128 + col] = fmaxf(acc, 0.f);
  }
}

// ---------------- precompute P_l (18x4), q_l (4): a_e = raw @ P + q ----------------
__global__ void k_prep(const float* __restrict__ gle, const float* __restrict__ atte,
                       const float* __restrict__ We, const float* __restrict__ be,
                       float* __restrict__ P, float* __restrict__ q) {
  __shared__ float M[128 * 4];
  int t = threadIdx.x;  // 128
  for (int l = 0; l < 3; l++) {
    {
      int k = t;
#pragma unroll
      for (int hh = 0; hh < 4; hh++) {
        float acc = 0.f;
        for (int c = 0; c < 32; c++)
          acc += gle[l * 16384 + k * 128 + hh * 32 + c] * atte[l * 128 + hh * 32 + c];
        M[k * 4 + hh] = acc;
      }
    }
    __syncthreads();
    if (t < 72) {
      int j = t >> 2, hh = t & 3;
      float acc = 0.f;
      for (int k = 0; k < 128; k++) acc += We[j * 128 + k] * M[k * 4 + hh];
      P[(l * 18 + j) * 4 + hh] = acc;
    }
    if (t < 4) {
      float acc = 0.f;
      for (int k = 0; k < 128; k++) acc += be[k] * M[k * 4 + t];
      q[l * 4 + t] = acc;
    }
    __syncthreads();
  }
}

// ---------------- degree histogram (int atomics only) ----------------
__global__ void k_deg(const int* __restrict__ dst, int* __restrict__ cnt, int E) {
  int i = blockIdx.x * 256 + threadIdx.x;
  if (i < E) atomicAdd(&cnt[dst[i]], 1);
}

// ------- per-edge a_e for all 3 layers (pure streaming, no atomics) -------
__global__ void k_ae(const float* __restrict__ enum_, const int* __restrict__ ec0,
                     const int* __restrict__ ec1,
                     const float* __restrict__ ee0, const float* __restrict__ ee1,
                     const float* __restrict__ P, const float* __restrict__ q,
                     float* __restrict__ ae, int E) {
  __shared__ float Ps[216];
  __shared__ float qs[12];
  int t = threadIdx.x;
  for (int i = t; i < 216; i += 256) Ps[i] = P[i];
  if (t < 12) qs[t] = q[t];
  __syncthreads();
  int i = blockIdx.x * 256 + t;
  if (i >= E) return;
  float raw[18];
  float4 nm = *(const float4*)(enum_ + (size_t)i * 4);
  raw[0] = nm.x; raw[1] = nm.y; raw[2] = nm.z; raw[3] = nm.w;
  int a0 = ec0[i], a1 = ec1[i];
  float4 eb0 = *(const float4*)(ee0 + a0 * 4);
  raw[4] = eb0.x; raw[5] = eb0.y; raw[6] = eb0.z; raw[7] = eb0.w;
#pragma unroll
  for (int j = 0; j < 10; j++) raw[8 + j] = ee1[a1 * 10 + j];
#pragma unroll
  for (int l = 0; l < 3; l++) {
    float o[4];
#pragma unroll
    for (int hh = 0; hh < 4; hh++) {
      float acc = qs[l * 4 + hh];
#pragma unroll
      for (int j = 0; j < 18; j++) acc += raw[j] * Ps[(l * 18 + j) * 4 + hh];
      o[hh] = acc;
    }
    *(float4*)(ae + (size_t)i * 12 + l * 4) = make_float4(o[0], o[1], o[2], o[3]);
  }
}

// self-loop a_e = mean of incoming a_e via CSR gather (no atomics)
__global__ void k_loopae(const float* __restrict__ ae, const int* __restrict__ rowptr,
                         const int* __restrict__ csr, float* __restrict__ aeL, int n) {
  int v = blockIdx.x * 256 + threadIdx.x;
  if (v >= n) return;
  int beg = rowptr[v], end = rowptr[v + 1];
  float4 s0 = make_float4(0.f, 0.f, 0.f, 0.f);
  float4 s1 = make_float4(0.f, 0.f, 0.f, 0.f);
  float4 s2 = make_float4(0.f, 0.f, 0.f, 0.f);
  for (int j = beg; j < end; j++) {
    int eid = csr[j];
    const float4* p = (const float4*)(ae + (size_t)eid * 12);
    float4 a = p[0], b = p[1], c = p[2];
    s0.x += a.x; s0.y += a.y; s0.z += a.z; s0.w += a.w;
    s1.x += b.x; s1.y += b.y; s1.z += b.z; s1.w += b.w;
    s2.x += c.x; s2.y += c.y; s2.z += c.z; s2.w += c.w;
  }
  float inv = (end > beg) ? 1.f / (float)(end - beg) : 0.f;
  float4* o = (float4*)(aeL + (size_t)v * 12);
  o[0] = make_float4(s0.x * inv, s0.y * inv, s0.z * inv, s0.w * inv);
  o[1] = make_float4(s1.x * inv, s1.y * inv, s1.z * inv, s1.w * inv);
  o[2] = make_float4(s2.x * inv, s2.y * inv, s2.z * inv, s2.w * inv);
}

// ---------------- CSR build: exclusive scan of cnt -> rowptr, then fill ----------------
__global__ void k_scan1(const int* __restrict__ cnt, int* __restrict__ excl,
                        int* __restrict__ bsum, int n) {
  __shared__ int sh[256];
  int t = threadIdx.x;
  int i = blockIdx.x * 256 + t;
  int v = (i < n) ? cnt[i] : 0;
  sh[t] = v;
  __syncthreads();
  for (int off = 1; off < 256; off <<= 1) {
    int add = (t >= off) ? sh[t - off] : 0;
    __syncthreads();
    sh[t] += add;
    __syncthreads();
  }
  if (i < n) excl[i] = sh[t] - v;
  if (t == 255) bsum[blockIdx.x] = sh[255];
}

__global__ void k_scan2(int* __restrict__ bsum, int nb) {
  __shared__ int sh[512];
  int t = threadIdx.x;
  int v = (t < nb) ? bsum[t] : 0;
  sh[t] = v;
  __syncthreads();
  for (int off = 1; off < 512; off <<= 1) {
    int add = (t >= off) ? sh[t - off] : 0;
    __syncthreads();
    sh[t] += add;
    __syncthreads();
  }
  if (t < nb) bsum[t] = sh[t] - v;
}

__global__ void k_scan3(int* __restrict__ rowptr, const int* __restrict__ boff,
                        int* __restrict__ cursor, int n, int E) {
  int i = blockIdx.x * 256 + threadIdx.x;
  if (i < n) {
    int val = rowptr[i] + boff[i >> 8];
    rowptr[i] = val;
    cursor[i] = val;
  }
  if (i == 0) rowptr[n] = E;
}

__global__ void k_fill(const int* __restrict__ dst, int* __restrict__ cursor,
                       int* __restrict__ csr, int E) {
  int i = blockIdx.x * 256 + threadIdx.x;
  if (i >= E) return;
  int pos = atomicAdd(&cursor[dst[i]], 1);
  csr[pos] = i;
}

// ------- x = h @ gat_lin[l]: register-tiled (4x4/thread, float4 LDS reads) + fused a_s/a_d -------
// Block: 64 rows x 64 cols (col-half = blockIdx.y). LT stored transposed [col][k] so
// both operands read as ds_read_b128 along k. Stride 132 -> 2-way bank conflicts (free).
__global__ void k_x(const float* __restrict__ h, const float* __restrict__ L_g,
                    const float* __restrict__ att_s, const float* __restrict__ att_d,
                    float* __restrict__ x, float* __restrict__ a_s,
                    float* __restrict__ a_d, int n) {
  __shared__ float LT[64 * XTP];  // [col][k]
  __shared__ float hr[64 * XTP];  // [row][k]
  int t = threadIdx.x;  // 256
  int ch = blockIdx.y;  // col half 0/1
  // stage LT transposed: LT[c][k] = L_g[k*128 + ch*64 + c]
  {
    int c = t & 63;
    for (int k = t >> 6; k < 128; k += 4)
      LT[c * XTP + k] = L_g[k * 128 + ch * 64 + c];
  }
  int tx = t & 15;   // 16 col-threads * 4 cols = 64 cols
  int ty = t >> 4;   // 16 row-threads * 4 rows = 64 rows
  int head = ch * 2 + (tx >> 3);
  float avs[4], avd[4];
#pragma unroll
  for (int c = 0; c < 4; c++) {
    avs[c] = att_s[ch * 64 + tx * 4 + c];
    avd[c] = att_d[ch * 64 + tx * 4 + c];
  }
  __syncthreads();
  for (int base = blockIdx.x * 64; base < n; base += gridDim.x * 64) {
    int nr = min(64, n - base);
    for (int i = t * 4; i < nr * 128; i += 1024) {
      float4 vv = *(const float4*)(h + (size_t)base * 128 + i);
      *(float4*)(hr + (i >> 7) * XTP + (i & 127)) = vv;
    }
    __syncthreads();
    float acc[4][4] = {{0.f}};
    for (int k = 0; k < 128; k += 4) {
      float4 a[4], b[4];
#pragma unroll
      for (int r = 0; r < 4; r++) a[r] = *(const float4*)(hr + (ty * 4 + r) * XTP + k);
#pragma unroll
      for (int c = 0; c < 4; c++) b[c] = *(const float4*)(LT + (tx * 4 + c) * XTP + k);
#pragma unroll
      for (int r = 0; r < 4; r++)
#pragma unroll
        for (int c = 0; c < 4; c++)
          acc[r][c] += a[r].x * b[c].x + a[r].y * b[c].y + a[r].z * b[c].z + a[r].w * b[c].w;
    }
#pragma unroll
    for (int r = 0; r < 4; r++) {
      int v = base + ty * 4 + r;
      if (v < n)
        *(float4*)(x + (size_t)v * 128 + ch * 64 + tx * 4) =
            make_float4(acc[r][0], acc[r][1], acc[r][2], acc[r][3]);
      // per-head attention dots: reduce over the 8 col-threads (32 cols) of this head
      float ps = acc[r][0] * avs[0] + acc[r][1] * avs[1] + acc[r][2] * avs[2] + acc[r][3] * avs[3];
      float pd = acc[r][0] * avd[0] + acc[r][1] * avd[1] + acc[r][2] * avd[2] + acc[r][3] * avd[3];
      ps += __shfl_xor(ps, 1); ps += __shfl_xor(ps, 2); ps += __shfl_xor(ps, 4);
      pd += __shfl_xor(pd, 1); pd += __shfl_xor(pd, 2); pd += __shfl_xor(pd, 4);
      if ((tx & 7) == 0 && v < n) {
        a_s[(size_t)v * 4 + head] = ps;
        a_d[(size_t)v * 4 + head] = pd;
      }
    }
    __syncthreads();
  }
}

// -------- per-dst online softmax + weighted gather; one wave per node; h updated in place --------
__global__ void k_agg(const float* __restrict__ x, const float* __restrict__ a_s,
                      const float* __restrict__ a_d, const float* __restrict__ ae,
                      const float* __restrict__ ae_loop,
                      const int* __restrict__ rowptr, const int* __restrict__ csr,
                      const int* __restrict__ srcarr, const float* __restrict__ bias,
                      float* __restrict__ hout, int n, int l) {
  int wid = threadIdx.x >> 6;
  int v = blockIdx.x * 4 + wid;
  if (v >= n) return;
  int lane = threadIdx.x & 63;
  float4 ad = *(const float4*)(a_d + (size_t)v * 4);
  float4 aeL = *(const float4*)(ae_loop + (size_t)v * 12 + l * 4);
  float4 asv = *(const float4*)(a_s + (size_t)v * 4);
  float m0 = leaky02(asv.x + ad.x + aeL.x);
  float m1 = leaky02(asv.y + ad.y + aeL.y);
  float m2 = leaky02(asv.z + ad.z + aeL.z);
  float m3 = leaky02(asv.w + ad.w + aeL.w);
  float s0 = 1.f, s1 = 1.f, s2 = 1.f, s3 = 1.f;
  float acc0 = x[(size_t)v * HID + lane];
  float acc1 = x[(size_t)v * HID + 64 + lane];
  int beg = rowptr[v], end = rowptr[v + 1];
  bool hi = (lane & 32) != 0;
  for (int j = beg; j < end; j++) {
    int eid = csr[j];
    int src = srcarr[eid];
    float4 aev = *(const float4*)(ae + (size_t)eid * 12 + l * 4);
    float4 asrc = *(const float4*)(a_s + (size_t)src * 4);
    float l0 = leaky02(asrc.x + ad.x + aev.x);
    float l1 = leaky02(asrc.y + ad.y + aev.y);
    float l2 = leaky02(asrc.z + ad.z + aev.z);
    float l3 = leaky02(asrc.w + ad.w + aev.w);
    float x0 = x[(size_t)src * HID + lane];
    float x1 = x[(size_t)src * HID + 64 + lane];
    float n0 = fmaxf(m0, l0), n1 = fmaxf(m1, l1), n2 = fmaxf(m2, l2), n3 = fmaxf(m3, l3);
    float c0 = __expf(m0 - n0), c1 = __expf(m1 - n1), c2 = __expf(m2 - n2), c3 = __expf(m3 - n3);
    float p0 = __expf(l0 - n0), p1 = __expf(l1 - n1), p2 = __expf(l2 - n2), p3 = __expf(l3 - n3);
    s0 = s0 * c0 + p0; s1 = s1 * c1 + p1; s2 = s2 * c2 + p2; s3 = s3 * c3 + p3;
    m0 = n0; m1 = n1; m2 = n2; m3 = n3;
    float cA = hi ? c1 : c0, pA = hi ? p1 : p0;
    float cB = hi ? c3 : c2, pB = hi ? p3 : p2;
    acc0 = acc0 * cA + pA * x0;
    acc1 = acc1 * cB + pB * x1;
  }
  float sA = hi ? s1 : s0;
  float sB = hi ? s3 : s2;
  float r0 = acc0 / sA + bias[l * HID + lane];
  float r1 = acc1 / sB + bias[l * HID + 64 + lane];
  hout[(size_t)v * HID + lane] = fmaxf(r0, 0.f);
  hout[(size_t)v * HID + 64 + lane] = fmaxf(r1, 0.f);
}

// ---------------- pooling: batch is sorted -> register accumulate, flush on change ----------------
__global__ void k_pool(const float* __restrict__ h, const int* __restrict__ batch,
                       float* __restrict__ g, int n) {
  int t = threadIdx.x;  // 128
  int per = (n + gridDim.x - 1) / gridDim.x;
  int start = blockIdx.x * per;
  int end = min(n, start + per);
  float acc = 0.f;
  int cur = -1;
  for (int v = start; v < end; v++) {
    int b = batch[v];
    if (b != cur) {
      if (cur >= 0) atomicAdd(&g[cur * 128 + t], acc);
      acc = 0.f;
      cur = b;
    }
    acc += h[(size_t)v * 128 + t];
  }
  if (cur >= 0) atomicAdd(&g[cur * 128 + t], acc);
}

// ---------------- head MLP on pooled g (8x128) ----------------
__global__ void k_head(const float* __restrict__ g, const float* __restrict__ Wr1,
                       const float* __restrict__ br1, const float* __restrict__ Wr2,
                       const float* __restrict__ br2, float* __restrict__ out, int G_) {
  __shared__ float gl[8 * 128];
  __shared__ float red[128];
  int t = threadIdx.x;  // 128
  for (int i = t; i < G_ * 128; i += 128) gl[i] = g[i];
  __syncthreads();
  for (int i = 0; i < G_; i++) {
    float acc = br1[t];
    for (int k = 0; k < 128; k++) acc += gl[i * 128 + k] * Wr1[k * 128 + t];
    float hv = fmaxf(acc, 0.f);
    red[t] = hv * Wr2[t];
    __syncthreads();
    if (t == 0) {
      float s = br2[0];
      for (int k = 0; k < 128; k++) s += red[k];
      out[i] = s;
    }
    __syncthreads();
  }
}

extern "C" void kernel_launch(void* const* d_in, const int* in_sizes, int n_in,
                              void* d_out, int out_size, void* d_ws, size_t ws_size,
                              hipStream_t stream) {
  const float* node_numeric = (const float*)d_in[0];
  const int* node_cat0 = (const int*)d_in[1];
  const int* node_cat1 = (const int*)d_in[2];
  const float* edge_numeric = (const float*)d_in[3];
  const int* edge_cat0 = (const int*)d_in[4];
  const int* edge_cat1 = (const int*)d_in[5];
  const int* edge_index = (const int*)d_in[6];
  const int* batch = (const int*)d_in[7];
  const float* recipe = (const float*)d_in[8];
  const float* emb_node0 = (const float*)d_in[9];
  const float* emb_node1 = (const float*)d_in[10];
  const float* emb_edge0 = (const float*)d_in[11];
  const float* emb_edge1 = (const float*)d_in[12];
  const float* W_in = (const float*)d_in[13];
  const float* b_in = (const float*)d_in[14];
  const float* W_edge = (const float*)d_in[15];
  const float* b_edge = (const float*)d_in[16];
  const float* gat_lin = (const float*)d_in[17];
  const float* gat_lin_edge = (const float*)d_in[18];
  const float* att_src = (const float*)d_in[19];
  const float* att_dst = (const float*)d_in[20];
  const float* att_edge = (const float*)d_in[21];
  const float* gat_bias = (const float*)d_in[22];
  const float* W_r1 = (const float*)d_in[23];
  const float* b_r1 = (const float*)d_in[24];
  const float* W_r2 = (const float*)d_in[25];
  const float* b_r2 = (const float*)d_in[26];

  int N = in_sizes[0] / 8;
  int E = in_sizes[3] / 4;
  int Gn = in_sizes[8] / 16;
  const int* srcArr = edge_index;
  const int* dstArr = edge_index + E;

  char* ws = (char*)d_ws;
  size_t o = 0;
  auto alloc = [&](size_t b) {
    char* p = ws + o;
    o = (o + b + 255) & ~(size_t)255;
    return p;
  };
  float* h = (float*)alloc((size_t)N * 128 * 4);
  float* x = (float*)alloc((size_t)N * 128 * 4);
  float* ae = (float*)alloc((size_t)E * 12 * 4);
  float* aeL = (float*)alloc((size_t)N * 12 * 4);
  float* a_s = (float*)alloc((size_t)N * 4 * 4);
  float* a_d = (float*)alloc((size_t)N * 4 * 4);
  float* P = (float*)alloc(216 * 4);
  float* q = (float*)alloc(12 * 4);
  int* cnt = (int*)alloc((size_t)N * 4);
  int* rowptr = (int*)alloc((size_t)(N + 1) * 4);
  int* cursor = (int*)alloc((size_t)N * 4);
  int* bsum = (int*)alloc(512 * 4);
  int* csr = (int*)alloc((size_t)E * 4);
  float* g = (float*)alloc((size_t)Gn * 128 * 4);
  (void)ws_size;

  (void)hipMemsetAsync(cnt, 0, (size_t)N * 4, stream);
  (void)hipMemsetAsync(g, 0, (size_t)Gn * 128 * 4, stream);

  int nbl = (N + 255) / 256;
  int ebl = (E + 255) / 256;

  k_enc<<<2048, 256, 0, stream>>>(node_numeric, node_cat0, node_cat1, batch, recipe,
                                  emb_node0, emb_node1, W_in, b_in, h, N);
  k_prep<<<1, 128, 0, stream>>>(gat_lin_edge, att_edge, W_edge, b_edge, P, q);
  k_deg<<<ebl, 256, 0, stream>>>(dstArr, cnt, E);
  k_ae<<<ebl, 256, 0, stream>>>(edge_numeric, edge_cat0, edge_cat1,
                                emb_edge0, emb_edge1, P, q, ae, E);
  k_scan1<<<nbl, 256, 0, stream>>>(cnt, rowptr, bsum, N);
  k_scan2<<<1, 512, 0, stream>>>(bsum, nbl);
  k_scan3<<<nbl, 256, 0, stream>>>(rowptr, bsum, cursor, N, E);
  k_fill<<<ebl, 256, 0, stream>>>(dstArr, cursor, csr, E);
  k_loopae<<<nbl, 256, 0, stream>>>(ae, rowptr, csr, aeL, N);

  for (int l = 0; l < 3; l++) {
    dim3 gx(256, 2);
    k_x<<<gx, 256, 0, stream>>>(h, gat_lin + l * 16384, att_src + l * 128,
                                att_dst + l * 128, x, a_s, a_d, N);
    k_agg<<<(N + 3) / 4, 256, 0, stream>>>(x, a_s, a_d, ae, aeL, rowptr, csr, srcArr,
                                           gat_bias, h, N, l);
  }
  k_pool<<<512, 128, 0, stream>>>(h, batch, g, N);
  k_head<<<1, 128, 0, stream>>>(g, W_r1, b_r1, W_r2, b_r2, (float*)d_out, Gn);
}

// Round 6
// 806.000 us; speedup vs baseline: 2.0165x; 1.1664x over previous
//
#include <hip/hip_runtime.h>
#include <math.h>

#define HID 128
#define XTP 132  // padded LDS stride (floats): 132%32=4 -> 2-way conflicts (free), float4-aligned

__device__ __forceinline__ float leaky02(float z) { return z >= 0.f ? z : 0.2f * z; }

// ---------------- node encoder: h = relu(concat(feat) @ W_in + b_in) ----------------
// No LDS, no barriers. 256 threads = 2 nodes (128 cols each); per-node loads are
// wave-uniform -> 1 transaction each. W column kept in registers (38 VGPR).
__global__ void k_enc(const float* __restrict__ nodenum, const int* __restrict__ c0,
                      const int* __restrict__ c1, const int* __restrict__ batch,
                      const float* __restrict__ recipe,
                      const float* __restrict__ e0, const float* __restrict__ e1,
                      const float* __restrict__ Win, const float* __restrict__ bin,
                      float* __restrict__ h, int n) {
  int t = threadIdx.x;  // 256
  int col = t & 127;
  int sub = t >> 7;  // 0/1: which node of the pair
  float w[38];
#pragma unroll
  for (int k = 0; k < 38; k++) w[k] = Win[k * 128 + col];
  float bias = bin[col];
  for (int v = blockIdx.x * 2 + sub; v < n; v += gridDim.x * 2) {
    float f[38];
    const float4* nm = (const float4*)(nodenum + (size_t)v * 8);
    float4 n0 = nm[0], n1 = nm[1];
    f[0] = n0.x; f[1] = n0.y; f[2] = n0.z; f[3] = n0.w;
    f[4] = n1.x; f[5] = n1.y; f[6] = n1.z; f[7] = n1.w;
    int a0 = c0[v], a1 = c1[v], b = batch[v];
    const float2* p0 = (const float2*)(e0 + a0 * 6);
    float2 q0 = p0[0], q1 = p0[1], q2 = p0[2];
    f[8] = q0.x; f[9] = q0.y; f[10] = q1.x; f[11] = q1.y; f[12] = q2.x; f[13] = q2.y;
    const float4* p1 = (const float4*)(e1 + a1 * 8);
    float4 r0 = p1[0], r1 = p1[1];
    f[14] = r0.x; f[15] = r0.y; f[16] = r0.z; f[17] = r0.w;
    f[18] = r1.x; f[19] = r1.y; f[20] = r1.z; f[21] = r1.w;
    const float4* pr = (const float4*)(recipe + b * 16);
    float4 c4;
    c4 = pr[0]; f[22] = c4.x; f[23] = c4.y; f[24] = c4.z; f[25] = c4.w;
    c4 = pr[1]; f[26] = c4.x; f[27] = c4.y; f[28] = c4.z; f[29] = c4.w;
    c4 = pr[2]; f[30] = c4.x; f[31] = c4.y; f[32] = c4.z; f[33] = c4.w;
    c4 = pr[3]; f[34] = c4.x; f[35] = c4.y; f[36] = c4.z; f[37] = c4.w;
    float acc = bias;
#pragma unroll
    for (int k = 0; k < 38; k++) acc += f[k] * w[k];
    h[(size_t)v * 128 + col] = fmaxf(acc, 0.f);
  }
}

// ---------------- precompute P_l (18x4), q_l (4): a_e = raw @ P + q ----------------
__global__ void k_prep(const float* __restrict__ gle, const float* __restrict__ atte,
                       const float* __restrict__ We, const float* __restrict__ be,
                       float* __restrict__ P, float* __restrict__ q) {
  __shared__ float M[128 * 4];
  int t = threadIdx.x;  // 128
  for (int l = 0; l < 3; l++) {
    {
      int k = t;
#pragma unroll
      for (int hh = 0; hh < 4; hh++) {
        float acc = 0.f;
        for (int c = 0; c < 32; c++)
          acc += gle[l * 16384 + k * 128 + hh * 32 + c] * atte[l * 128 + hh * 32 + c];
        M[k * 4 + hh] = acc;
      }
    }
    __syncthreads();
    if (t < 72) {
      int j = t >> 2, hh = t & 3;
      float acc = 0.f;
      for (int k = 0; k < 128; k++) acc += We[j * 128 + k] * M[k * 4 + hh];
      P[(l * 18 + j) * 4 + hh] = acc;
    }
    if (t < 4) {
      float acc = 0.f;
      for (int k = 0; k < 128; k++) acc += be[k] * M[k * 4 + t];
      q[l * 4 + t] = acc;
    }
    __syncthreads();
  }
}

// ---------------- degree histogram (int atomics only) ----------------
__global__ void k_deg(const int* __restrict__ dst, int* __restrict__ cnt, int E) {
  int i = blockIdx.x * 256 + threadIdx.x;
  if (i < E) atomicAdd(&cnt[dst[i]], 1);
}

// ------- per-edge a_e for all 3 layers (pure streaming, no atomics) -------
__global__ void k_ae(const float* __restrict__ enum_, const int* __restrict__ ec0,
                     const int* __restrict__ ec1,
                     const float* __restrict__ ee0, const float* __restrict__ ee1,
                     const float* __restrict__ P, const float* __restrict__ q,
                     float* __restrict__ ae, int E) {
  __shared__ float Ps[216];
  __shared__ float qs[12];
  int t = threadIdx.x;
  for (int i = t; i < 216; i += 256) Ps[i] = P[i];
  if (t < 12) qs[t] = q[t];
  __syncthreads();
  int i = blockIdx.x * 256 + t;
  if (i >= E) return;
  float raw[18];
  float4 nm = *(const float4*)(enum_ + (size_t)i * 4);
  raw[0] = nm.x; raw[1] = nm.y; raw[2] = nm.z; raw[3] = nm.w;
  int a0 = ec0[i], a1 = ec1[i];
  float4 eb0 = *(const float4*)(ee0 + a0 * 4);
  raw[4] = eb0.x; raw[5] = eb0.y; raw[6] = eb0.z; raw[7] = eb0.w;
#pragma unroll
  for (int j = 0; j < 10; j++) raw[8 + j] = ee1[a1 * 10 + j];
#pragma unroll
  for (int l = 0; l < 3; l++) {
    float o[4];
#pragma unroll
    for (int hh = 0; hh < 4; hh++) {
      float acc = qs[l * 4 + hh];
#pragma unroll
      for (int j = 0; j < 18; j++) acc += raw[j] * Ps[(l * 18 + j) * 4 + hh];
      o[hh] = acc;
    }
    *(float4*)(ae + (size_t)i * 12 + l * 4) = make_float4(o[0], o[1], o[2], o[3]);
  }
}

// self-loop a_e = mean of incoming a_e via CSR gather (no atomics)
__global__ void k_loopae(const float* __restrict__ ae, const int* __restrict__ rowptr,
                         const int* __restrict__ csr, float* __restrict__ aeL, int n) {
  int v = blockIdx.x * 256 + threadIdx.x;
  if (v >= n) return;
  int beg = rowptr[v], end = rowptr[v + 1];
  float4 s0 = make_float4(0.f, 0.f, 0.f, 0.f);
  float4 s1 = make_float4(0.f, 0.f, 0.f, 0.f);
  float4 s2 = make_float4(0.f, 0.f, 0.f, 0.f);
  for (int j = beg; j < end; j++) {
    int eid = csr[j];
    const float4* p = (const float4*)(ae + (size_t)eid * 12);
    float4 a = p[0], b = p[1], c = p[2];
    s0.x += a.x; s0.y += a.y; s0.z += a.z; s0.w += a.w;
    s1.x += b.x; s1.y += b.y; s1.z += b.z; s1.w += b.w;
    s2.x += c.x; s2.y += c.y; s2.z += c.z; s2.w += c.w;
  }
  float inv = (end > beg) ? 1.f / (float)(end - beg) : 0.f;
  float4* o = (float4*)(aeL + (size_t)v * 12);
  o[0] = make_float4(s0.x * inv, s0.y * inv, s0.z * inv, s0.w * inv);
  o[1] = make_float4(s1.x * inv, s1.y * inv, s1.z * inv, s1.w * inv);
  o[2] = make_float4(s2.x * inv, s2.y * inv, s2.z * inv, s2.w * inv);
}

// ---------------- CSR build: exclusive scan of cnt -> rowptr, then fill ----------------
__global__ void k_scan1(const int* __restrict__ cnt, int* __restrict__ excl,
                        int* __restrict__ bsum, int n) {
  __shared__ int sh[256];
  int t = threadIdx.x;
  int i = blockIdx.x * 256 + t;
  int v = (i < n) ? cnt[i] : 0;
  sh[t] = v;
  __syncthreads();
  for (int off = 1; off < 256; off <<= 1) {
    int add = (t >= off) ? sh[t - off] : 0;
    __syncthreads();
    sh[t] += add;
    __syncthreads();
  }
  if (i < n) excl[i] = sh[t] - v;
  if (t == 255) bsum[blockIdx.x] = sh[255];
}

__global__ void k_scan2(int* __restrict__ bsum, int nb) {
  __shared__ int sh[512];
  int t = threadIdx.x;
  int v = (t < nb) ? bsum[t] : 0;
  sh[t] = v;
  __syncthreads();
  for (int off = 1; off < 512; off <<= 1) {
    int add = (t >= off) ? sh[t - off] : 0;
    __syncthreads();
    sh[t] += add;
    __syncthreads();
  }
  if (t < nb) bsum[t] = sh[t] - v;
}

__global__ void k_scan3(int* __restrict__ rowptr, const int* __restrict__ boff,
                        int* __restrict__ cursor, int n, int E) {
  int i = blockIdx.x * 256 + threadIdx.x;
  if (i < n) {
    int val = rowptr[i] + boff[i >> 8];
    rowptr[i] = val;
    cursor[i] = val;
  }
  if (i == 0) rowptr[n] = E;
}

__global__ void k_fill(const int* __restrict__ dst, int* __restrict__ cursor,
                       int* __restrict__ csr, int E) {
  int i = blockIdx.x * 256 + threadIdx.x;
  if (i >= E) return;
  int pos = atomicAdd(&cursor[dst[i]], 1);
  csr[pos] = i;
}

// ------- x = h @ gat_lin[l]: register-tiled (4x4/thread, float4 LDS reads) + fused a_s/a_d -------
// Block: 64 rows x 64 cols (col-half = blockIdx.y). LT stored transposed [col][k] so
// both operands read as ds_read_b128 along k. Stride 132 -> 2-way bank conflicts (free).
__global__ void k_x(const float* __restrict__ h, const float* __restrict__ L_g,
                    const float* __restrict__ att_s, const float* __restrict__ att_d,
                    float* __restrict__ x, float* __restrict__ a_s,
                    float* __restrict__ a_d, int n) {
  __shared__ float LT[64 * XTP];  // [col][k]
  __shared__ float hr[64 * XTP];  // [row][k]
  int t = threadIdx.x;  // 256
  int ch = blockIdx.y;  // col half 0/1
  // stage LT transposed: LT[c][k] = L_g[k*128 + ch*64 + c]
  {
    int c = t & 63;
    for (int k = t >> 6; k < 128; k += 4)
      LT[c * XTP + k] = L_g[k * 128 + ch * 64 + c];
  }
  int tx = t & 15;   // 16 col-threads * 4 cols = 64 cols
  int ty = t >> 4;   // 16 row-threads * 4 rows = 64 rows
  int head = ch * 2 + (tx >> 3);
  float avs[4], avd[4];
#pragma unroll
  for (int c = 0; c < 4; c++) {
    avs[c] = att_s[ch * 64 + tx * 4 + c];
    avd[c] = att_d[ch * 64 + tx * 4 + c];
  }
  __syncthreads();
  for (int base = blockIdx.x * 64; base < n; base += gridDim.x * 64) {
    int nr = min(64, n - base);
    for (int i = t * 4; i < nr * 128; i += 1024) {
      float4 vv = *(const float4*)(h + (size_t)base * 128 + i);
      *(float4*)(hr + (i >> 7) * XTP + (i & 127)) = vv;
    }
    __syncthreads();
    float acc[4][4] = {{0.f}};
    for (int k = 0; k < 128; k += 4) {
      float4 a[4], b[4];
#pragma unroll
      for (int r = 0; r < 4; r++) a[r] = *(const float4*)(hr + (ty * 4 + r) * XTP + k);
#pragma unroll
      for (int c = 0; c < 4; c++) b[c] = *(const float4*)(LT + (tx * 4 + c) * XTP + k);
#pragma unroll
      for (int r = 0; r < 4; r++)
#pragma unroll
        for (int c = 0; c < 4; c++)
          acc[r][c] += a[r].x * b[c].x + a[r].y * b[c].y + a[r].z * b[c].z + a[r].w * b[c].w;
    }
#pragma unroll
    for (int r = 0; r < 4; r++) {
      int v = base + ty * 4 + r;
      if (v < n)
        *(float4*)(x + (size_t)v * 128 + ch * 64 + tx * 4) =
            make_float4(acc[r][0], acc[r][1], acc[r][2], acc[r][3]);
      // per-head attention dots: reduce over the 8 col-threads (32 cols) of this head
      float ps = acc[r][0] * avs[0] + acc[r][1] * avs[1] + acc[r][2] * avs[2] + acc[r][3] * avs[3];
      float pd = acc[r][0] * avd[0] + acc[r][1] * avd[1] + acc[r][2] * avd[2] + acc[r][3] * avd[3];
      ps += __shfl_xor(ps, 1); ps += __shfl_xor(ps, 2); ps += __shfl_xor(ps, 4);
      pd += __shfl_xor(pd, 1); pd += __shfl_xor(pd, 2); pd += __shfl_xor(pd, 4);
      if ((tx & 7) == 0 && v < n) {
        a_s[(size_t)v * 4 + head] = ps;
        a_d[(size_t)v * 4 + head] = pd;
      }
    }
    __syncthreads();
  }
}

// -------- per-dst softmax: lane-parallel logits (lane = edge_slot*4 + head), chunked online --------
// One wave per node. Per chunk of <=16 edges: parallel logit/exp, shfl-butterfly max/sum over
// edge lanes (xor bits 2..5 preserve head bits 0..1), ONE acc rescale per chunk, then a light
// aggregation loop: readlane(src) + shfl-broadcast(p) + 2 coalesced x-loads + 2 FMA per edge.
__global__ void k_agg(const float* __restrict__ x, const float* __restrict__ a_s,
                      const float* __restrict__ a_d, const float* __restrict__ ae,
                      const float* __restrict__ ae_loop,
                      const int* __restrict__ rowptr, const int* __restrict__ csr,
                      const int* __restrict__ srcarr, const float* __restrict__ bias,
                      float* __restrict__ hout, int n, int l) {
  int wid = threadIdx.x >> 6;
  int v = blockIdx.x * 4 + wid;
  if (v >= n) return;
  int lane = threadIdx.x & 63;
  int el = lane >> 2;  // edge slot 0..15
  int hh = lane & 3;   // head 0..3
  // per-lane own-head scalars (4 consecutive floats across 4 lanes -> coalesced)
  float ad_own = a_d[(size_t)v * 4 + hh];
  float as_own = a_s[(size_t)v * 4 + hh];
  float aeL_own = ae_loop[(size_t)v * 12 + l * 4 + hh];
  float m_own = leaky02(as_own + ad_own + aeL_own);  // self-loop logit, own head
  float s[4];
#pragma unroll
  for (int h2 = 0; h2 < 4; h2++) s[h2] = 1.f;  // self contributes exp(0)=1
  float acc0 = x[(size_t)v * 128 + lane];
  float acc1 = x[(size_t)v * 128 + 64 + lane];
  int beg = rowptr[v], end = rowptr[v + 1];
  int headA = lane >> 5;  // 0/1: col=lane -> head0/1; col+64 -> head2/3
  for (int cb = beg; cb < end; cb += 16) {
    int ne = end - cb;
    if (ne > 16) ne = 16;
    float logit = -1e30f;
    int srcE = 0;
    if (el < ne) {
      int eid = csr[cb + el];
      srcE = srcarr[eid];
      float asrc = a_s[(size_t)srcE * 4 + hh];
      float aev = ae[(size_t)eid * 12 + l * 4 + hh];
      logit = leaky02(asrc + ad_own + aev);
    }
    // per-head chunk max over edge lanes
    float cm = logit;
    cm = fmaxf(cm, __shfl_xor(cm, 4));
    cm = fmaxf(cm, __shfl_xor(cm, 8));
    cm = fmaxf(cm, __shfl_xor(cm, 16));
    cm = fmaxf(cm, __shfl_xor(cm, 32));
    float mn_own = fmaxf(m_own, cm);
    float p = (el < ne) ? __expf(logit - mn_own) : 0.f;
    float ps = p;
    ps += __shfl_xor(ps, 4);
    ps += __shfl_xor(ps, 8);
    ps += __shfl_xor(ps, 16);
    ps += __shfl_xor(ps, 32);
    float c_own = __expf(m_own - mn_own);
    m_own = mn_own;
    // head h's (c, psum) live in lane h; broadcast to all
    float c[4];
#pragma unroll
    for (int h2 = 0; h2 < 4; h2++) {
      c[h2] = __shfl(c_own, h2);
      s[h2] = s[h2] * c[h2] + __shfl(ps, h2);
    }
    float cA = headA ? c[1] : c[0];
    float cB = headA ? c[3] : c[2];
    acc0 *= cA;
    acc1 *= cB;
    for (int e = 0; e < ne; e++) {
      int se = __builtin_amdgcn_readlane(srcE, e * 4);
      float pA = __shfl(p, e * 4 + headA);
      float pB = __shfl(p, e * 4 + 2 + headA);
      float x0 = x[(size_t)se * 128 + lane];
      float x1 = x[(size_t)se * 128 + 64 + lane];
      acc0 += pA * x0;
      acc1 += pB * x1;
    }
  }
  float sA = headA ? s[1] : s[0];
  float sB = headA ? s[3] : s[2];
  float r0 = acc0 / sA + bias[l * HID + lane];
  float r1 = acc1 / sB + bias[l * HID + 64 + lane];
  hout[(size_t)v * HID + lane] = fmaxf(r0, 0.f);
  hout[(size_t)v * HID + 64 + lane] = fmaxf(r1, 0.f);
}

// ---------------- pooling: batch is sorted -> register accumulate, flush on change ----------------
__global__ void k_pool(const float* __restrict__ h, const int* __restrict__ batch,
                       float* __restrict__ g, int n) {
  int t = threadIdx.x;  // 128
  int per = (n + gridDim.x - 1) / gridDim.x;
  int start = blockIdx.x * per;
  int end = min(n, start + per);
  float acc = 0.f;
  int cur = -1;
  for (int v = start; v < end; v++) {
    int b = batch[v];
    if (b != cur) {
      if (cur >= 0) atomicAdd(&g[cur * 128 + t], acc);
      acc = 0.f;
      cur = b;
    }
    acc += h[(size_t)v * 128 + t];
  }
  if (cur >= 0) atomicAdd(&g[cur * 128 + t], acc);
}

// ---------------- head MLP on pooled g (8x128) ----------------
__global__ void k_head(const float* __restrict__ g, const float* __restrict__ Wr1,
                       const float* __restrict__ br1, const float* __restrict__ Wr2,
                       const float* __restrict__ br2, float* __restrict__ out, int G_) {
  __shared__ float gl[8 * 128];
  __shared__ float red[128];
  int t = threadIdx.x;  // 128
  for (int i = t; i < G_ * 128; i += 128) gl[i] = g[i];
  __syncthreads();
  for (int i = 0; i < G_; i++) {
    float acc = br1[t];
    for (int k = 0; k < 128; k++) acc += gl[i * 128 + k] * Wr1[k * 128 + t];
    float hv = fmaxf(acc, 0.f);
    red[t] = hv * Wr2[t];
    __syncthreads();
    if (t == 0) {
      float s = br2[0];
      for (int k = 0; k < 128; k++) s += red[k];
      out[i] = s;
    }
    __syncthreads();
  }
}

extern "C" void kernel_launch(void* const* d_in, const int* in_sizes, int n_in,
                              void* d_out, int out_size, void* d_ws, size_t ws_size,
                              hipStream_t stream) {
  const float* node_numeric = (const float*)d_in[0];
  const int* node_cat0 = (const int*)d_in[1];
  const int* node_cat1 = (const int*)d_in[2];
  const float* edge_numeric = (const float*)d_in[3];
  const int* edge_cat0 = (const int*)d_in[4];
  const int* edge_cat1 = (const int*)d_in[5];
  const int* edge_index = (const int*)d_in[6];
  const int* batch = (const int*)d_in[7];
  const float* recipe = (const float*)d_in[8];
  const float* emb_node0 = (const float*)d_in[9];
  const float* emb_node1 = (const float*)d_in[10];
  const float* emb_edge0 = (const float*)d_in[11];
  const float* emb_edge1 = (const float*)d_in[12];
  const float* W_in = (const float*)d_in[13];
  const float* b_in = (const float*)d_in[14];
  const float* W_edge = (const float*)d_in[15];
  const float* b_edge = (const float*)d_in[16];
  const float* gat_lin = (const float*)d_in[17];
  const float* gat_lin_edge = (const float*)d_in[18];
  const float* att_src = (const float*)d_in[19];
  const float* att_dst = (const float*)d_in[20];
  const float* att_edge = (const float*)d_in[21];
  const float* gat_bias = (const float*)d_in[22];
  const float* W_r1 = (const float*)d_in[23];
  const float* b_r1 = (const float*)d_in[24];
  const float* W_r2 = (const float*)d_in[25];
  const float* b_r2 = (const float*)d_in[26];

  int N = in_sizes[0] / 8;
  int E = in_sizes[3] / 4;
  int Gn = in_sizes[8] / 16;
  const int* srcArr = edge_index;
  const int* dstArr = edge_index + E;

  char* ws = (char*)d_ws;
  size_t o = 0;
  auto alloc = [&](size_t b) {
    char* p = ws + o;
    o = (o + b + 255) & ~(size_t)255;
    return p;
  };
  float* h = (float*)alloc((size_t)N * 128 * 4);
  float* x = (float*)alloc((size_t)N * 128 * 4);
  float* ae = (float*)alloc((size_t)E * 12 * 4);
  float* aeL = (float*)alloc((size_t)N * 12 * 4);
  float* a_s = (float*)alloc((size_t)N * 4 * 4);
  float* a_d = (float*)alloc((size_t)N * 4 * 4);
  float* P = (float*)alloc(216 * 4);
  float* q = (float*)alloc(12 * 4);
  int* cnt = (int*)alloc((size_t)N * 4);
  int* rowptr = (int*)alloc((size_t)(N + 1) * 4);
  int* cursor = (int*)alloc((size_t)N * 4);
  int* bsum = (int*)alloc(512 * 4);
  int* csr = (int*)alloc((size_t)E * 4);
  float* g = (float*)alloc((size_t)Gn * 128 * 4);
  (void)ws_size;

  (void)hipMemsetAsync(cnt, 0, (size_t)N * 4, stream);
  (void)hipMemsetAsync(g, 0, (size_t)Gn * 128 * 4, stream);

  int nbl = (N + 255) / 256;
  int ebl = (E + 255) / 256;

  k_enc<<<2048, 256, 0, stream>>>(node_numeric, node_cat0, node_cat1, batch, recipe,
                                  emb_node0, emb_node1, W_in, b_in, h, N);
  k_prep<<<1, 128, 0, stream>>>(gat_lin_edge, att_edge, W_edge, b_edge, P, q);
  k_deg<<<ebl, 256, 0, stream>>>(dstArr, cnt, E);
  k_ae<<<ebl, 256, 0, stream>>>(edge_numeric, edge_cat0, edge_cat1,
                                emb_edge0, emb_edge1, P, q, ae, E);
  k_scan1<<<nbl, 256, 0, stream>>>(cnt, rowptr, bsum, N);
  k_scan2<<<1, 512, 0, stream>>>(bsum, nbl);
  k_scan3<<<nbl, 256, 0, stream>>>(rowptr, bsum, cursor, N, E);
  k_fill<<<ebl, 256, 0, stream>>>(dstArr, cursor, csr, E);
  k_loopae<<<nbl, 256, 0, stream>>>(ae, rowptr, csr, aeL, N);

  for (int l = 0; l < 3; l++) {
    dim3 gx(256, 2);
    k_x<<<gx, 256, 0, stream>>>(h, gat_lin + l * 16384, att_src + l * 128,
                                att_dst + l * 128, x, a_s, a_d, N);
    k_agg<<<(N + 3) / 4, 256, 0, stream>>>(x, a_s, a_d, ae, aeL, rowptr, csr, srcArr,
                                           gat_bias, h, N, l);
  }
  k_pool<<<512, 128, 0, stream>>>(h, batch, g, N);
  k_head<<<1, 128, 0, stream>>>(g, W_r1, b_r1, W_r2, b_r2, (float*)d_out, Gn);
}

// Round 7
// 588.876 us; speedup vs baseline: 2.7601x; 1.3687x over previous
//
#include <hip/hip_runtime.h>
#include <math.h>

#define HID 128

typedef float f32x4 __attribute__((ext_vector_type(4)));
typedef short bf16x8 __attribute__((ext_vector_type(8)));
typedef unsigned int uint32;
typedef unsigned short ushort16;

__device__ __forceinline__ float leaky02(float z) { return z >= 0.f ? z : 0.2f * z; }
__device__ __forceinline__ unsigned short f2bf(float f) {
  uint32 u = __float_as_uint(f);
  u = (u + 0x7fff + ((u >> 16) & 1)) >> 16;  // RNE
  return (unsigned short)u;
}
__device__ __forceinline__ float bf2f(uint32 us) { return __uint_as_float(us << 16); }

// ---------------- node encoder: h_bf = relu(concat(feat) @ W_in + b_in) ----------------
__global__ void k_enc(const float* __restrict__ nodenum, const int* __restrict__ c0,
                      const int* __restrict__ c1, const int* __restrict__ batch,
                      const float* __restrict__ recipe,
                      const float* __restrict__ e0, const float* __restrict__ e1,
                      const float* __restrict__ Win, const float* __restrict__ bin,
                      unsigned short* __restrict__ hb, int n) {
  int t = threadIdx.x;  // 256
  int col = t & 127;
  int sub = t >> 7;
  float w[38];
#pragma unroll
  for (int k = 0; k < 38; k++) w[k] = Win[k * 128 + col];
  float bias = bin[col];
  for (int v = blockIdx.x * 2 + sub; v < n; v += gridDim.x * 2) {
    float f[38];
    const float4* nm = (const float4*)(nodenum + (size_t)v * 8);
    float4 n0 = nm[0], n1 = nm[1];
    f[0] = n0.x; f[1] = n0.y; f[2] = n0.z; f[3] = n0.w;
    f[4] = n1.x; f[5] = n1.y; f[6] = n1.z; f[7] = n1.w;
    int a0 = c0[v], a1 = c1[v], b = batch[v];
    const float2* p0 = (const float2*)(e0 + a0 * 6);
    float2 q0 = p0[0], q1 = p0[1], q2 = p0[2];
    f[8] = q0.x; f[9] = q0.y; f[10] = q1.x; f[11] = q1.y; f[12] = q2.x; f[13] = q2.y;
    const float4* p1 = (const float4*)(e1 + a1 * 8);
    float4 r0 = p1[0], r1 = p1[1];
    f[14] = r0.x; f[15] = r0.y; f[16] = r0.z; f[17] = r0.w;
    f[18] = r1.x; f[19] = r1.y; f[20] = r1.z; f[21] = r1.w;
    const float4* pr = (const float4*)(recipe + b * 16);
    float4 c4;
    c4 = pr[0]; f[22] = c4.x; f[23] = c4.y; f[24] = c4.z; f[25] = c4.w;
    c4 = pr[1]; f[26] = c4.x; f[27] = c4.y; f[28] = c4.z; f[29] = c4.w;
    c4 = pr[2]; f[30] = c4.x; f[31] = c4.y; f[32] = c4.z; f[33] = c4.w;
    c4 = pr[3]; f[34] = c4.x; f[35] = c4.y; f[36] = c4.z; f[37] = c4.w;
    float acc = bias;
#pragma unroll
    for (int k = 0; k < 38; k++) acc += f[k] * w[k];
    hb[(size_t)v * 128 + col] = f2bf(fmaxf(acc, 0.f));
  }
}

// ---------------- precompute P_l (18x4), q_l (4): a_e = raw @ P + q ----------------
__global__ void k_prep(const float* __restrict__ gle, const float* __restrict__ atte,
                       const float* __restrict__ We, const float* __restrict__ be,
                       float* __restrict__ P, float* __restrict__ q) {
  __shared__ float M[128 * 4];
  int t = threadIdx.x;  // 128
  for (int l = 0; l < 3; l++) {
    {
      int k = t;
#pragma unroll
      for (int hh = 0; hh < 4; hh++) {
        float acc = 0.f;
        for (int c = 0; c < 32; c++)
          acc += gle[l * 16384 + k * 128 + hh * 32 + c] * atte[l * 128 + hh * 32 + c];
        M[k * 4 + hh] = acc;
      }
    }
    __syncthreads();
    if (t < 72) {
      int j = t >> 2, hh = t & 3;
      float acc = 0.f;
      for (int k = 0; k < 128; k++) acc += We[j * 128 + k] * M[k * 4 + hh];
      P[(l * 18 + j) * 4 + hh] = acc;
    }
    if (t < 4) {
      float acc = 0.f;
      for (int k = 0; k < 128; k++) acc += be[k] * M[k * 4 + t];
      q[l * 4 + t] = acc;
    }
    __syncthreads();
  }
}

// ---------------- degree histogram (int atomics only) ----------------
__global__ void k_deg(const int* __restrict__ dst, int* __restrict__ cnt, int E) {
  int i = blockIdx.x * 256 + threadIdx.x;
  if (i < E) atomicAdd(&cnt[dst[i]], 1);
}

// ------- per-edge a_e for all 3 layers (pure streaming, no atomics) -------
__global__ void k_ae(const float* __restrict__ enum_, const int* __restrict__ ec0,
                     const int* __restrict__ ec1,
                     const float* __restrict__ ee0, const float* __restrict__ ee1,
                     const float* __restrict__ P, const float* __restrict__ q,
                     float* __restrict__ ae, int E) {
  __shared__ float Ps[216];
  __shared__ float qs[12];
  int t = threadIdx.x;
  for (int i = t; i < 216; i += 256) Ps[i] = P[i];
  if (t < 12) qs[t] = q[t];
  __syncthreads();
  int i = blockIdx.x * 256 + t;
  if (i >= E) return;
  float raw[18];
  float4 nm = *(const float4*)(enum_ + (size_t)i * 4);
  raw[0] = nm.x; raw[1] = nm.y; raw[2] = nm.z; raw[3] = nm.w;
  int a0 = ec0[i], a1 = ec1[i];
  float4 eb0 = *(const float4*)(ee0 + a0 * 4);
  raw[4] = eb0.x; raw[5] = eb0.y; raw[6] = eb0.z; raw[7] = eb0.w;
#pragma unroll
  for (int j = 0; j < 10; j++) raw[8 + j] = ee1[a1 * 10 + j];
#pragma unroll
  for (int l = 0; l < 3; l++) {
    float o[4];
#pragma unroll
    for (int hh = 0; hh < 4; hh++) {
      float acc = qs[l * 4 + hh];
#pragma unroll
      for (int j = 0; j < 18; j++) acc += raw[j] * Ps[(l * 18 + j) * 4 + hh];
      o[hh] = acc;
    }
    *(float4*)(ae + (size_t)i * 12 + l * 4) = make_float4(o[0], o[1], o[2], o[3]);
  }
}

// self-loop a_e = mean of incoming a_e via CSR gather (no atomics)
__global__ void k_loopae(const float* __restrict__ ae, const int* __restrict__ rowptr,
                         const int* __restrict__ csr, float* __restrict__ aeL, int n) {
  int v = blockIdx.x * 256 + threadIdx.x;
  if (v >= n) return;
  int beg = rowptr[v], end = rowptr[v + 1];
  float4 s0 = make_float4(0.f, 0.f, 0.f, 0.f);
  float4 s1 = make_float4(0.f, 0.f, 0.f, 0.f);
  float4 s2 = make_float4(0.f, 0.f, 0.f, 0.f);
  for (int j = beg; j < end; j++) {
    int eid = csr[j];
    const float4* p = (const float4*)(ae + (size_t)eid * 12);
    float4 a = p[0], b = p[1], c = p[2];
    s0.x += a.x; s0.y += a.y; s0.z += a.z; s0.w += a.w;
    s1.x += b.x; s1.y += b.y; s1.z += b.z; s1.w += b.w;
    s2.x += c.x; s2.y += c.y; s2.z += c.z; s2.w += c.w;
  }
  float inv = (end > beg) ? 1.f / (float)(end - beg) : 0.f;
  float4* o = (float4*)(aeL + (size_t)v * 12);
  o[0] = make_float4(s0.x * inv, s0.y * inv, s0.z * inv, s0.w * inv);
  o[1] = make_float4(s1.x * inv, s1.y * inv, s1.z * inv, s1.w * inv);
  o[2] = make_float4(s2.x * inv, s2.y * inv, s2.z * inv, s2.w * inv);
}

// ---------------- CSR build: exclusive scan of cnt -> rowptr, then fill ----------------
__global__ void k_scan1(const int* __restrict__ cnt, int* __restrict__ excl,
                        int* __restrict__ bsum, int n) {
  __shared__ int sh[256];
  int t = threadIdx.x;
  int i = blockIdx.x * 256 + t;
  int v = (i < n) ? cnt[i] : 0;
  sh[t] = v;
  __syncthreads();
  for (int off = 1; off < 256; off <<= 1) {
    int add = (t >= off) ? sh[t - off] : 0;
    __syncthreads();
    sh[t] += add;
    __syncthreads();
  }
  if (i < n) excl[i] = sh[t] - v;
  if (t == 255) bsum[blockIdx.x] = sh[255];
}

__global__ void k_scan2(int* __restrict__ bsum, int nb) {
  __shared__ int sh[512];
  int t = threadIdx.x;
  int v = (t < nb) ? bsum[t] : 0;
  sh[t] = v;
  __syncthreads();
  for (int off = 1; off < 512; off <<= 1) {
    int add = (t >= off) ? sh[t - off] : 0;
    __syncthreads();
    sh[t] += add;
    __syncthreads();
  }
  if (t < nb) bsum[t] = sh[t] - v;
}

__global__ void k_scan3(int* __restrict__ rowptr, const int* __restrict__ boff,
                        int* __restrict__ cursor, int n, int E) {
  int i = blockIdx.x * 256 + threadIdx.x;
  if (i < n) {
    int val = rowptr[i] + boff[i >> 8];
    rowptr[i] = val;
    cursor[i] = val;
  }
  if (i == 0) rowptr[n] = E;
}

__global__ void k_fill(const int* __restrict__ dst, int* __restrict__ cursor,
                       int* __restrict__ csr, int E) {
  int i = blockIdx.x * 256 + threadIdx.x;
  if (i >= E) return;
  int pos = atomicAdd(&cursor[dst[i]], 1);
  csr[pos] = i;
}

// ------- x = h @ gat_lin[l] via bf16 MFMA 16x16x32; B held in 64 VGPRs; h in swizzled LDS -------
// grid (Gx, 2): blockIdx.y = col half. Block 256 = 4 waves; wave w owns rows [w*16, w*16+16)
// of each 64-row tile, cols = half (4 col-tiles of 16). Fragment layout (m89/m97-verified):
// A: row=lane&15, k=(lane>>4)*8+j ; B: col=lane&15, same k ; C/D: col=lane&15, row=(lane>>4)*4+reg.
// LDS swizzle: 16B-chunk index c stored at c^(r&7) -> A-reads 2-way conflicts (free).
__global__ void k_x(const unsigned short* __restrict__ hb, const float* __restrict__ W,
                    const float* __restrict__ att_s, const float* __restrict__ att_d,
                    unsigned short* __restrict__ xb, float* __restrict__ a_s,
                    float* __restrict__ a_d, int n) {
  __shared__ unsigned short hs[64 * 128];
  int t = threadIdx.x;  // 256
  int ch = blockIdx.y;
  int w = t >> 6, l = t & 63;
  int lr = l & 15, lg = l >> 4;
  // B fragments: bfrag[ct][ks] -> col = ch*64+ct*16+lr, k = ks*32+lg*8+j (f32 -> bf16)
  bf16x8 bfrag[4][4];
#pragma unroll
  for (int ct = 0; ct < 4; ct++) {
#pragma unroll
    for (int ks = 0; ks < 4; ks++) {
      int col = ch * 64 + ct * 16 + lr;
      int k0 = ks * 32 + lg * 8;
      bf16x8 fr;
#pragma unroll
      for (int j = 0; j < 8; j++) fr[j] = (short)f2bf(W[(k0 + j) * 128 + col]);
      bfrag[ct][ks] = fr;
    }
  }
  float avs[4], avd[4];
#pragma unroll
  for (int ct = 0; ct < 4; ct++) {
    avs[ct] = att_s[ch * 64 + ct * 16 + lr];
    avd[ct] = att_d[ch * 64 + ct * 16 + lr];
  }
  for (int tb = blockIdx.x * 64; tb < n; tb += gridDim.x * 64) {
    __syncthreads();
    // stage 64 rows x 128 bf16 (16KB), swizzled chunks
#pragma unroll
    for (int i = 0; i < 4; i++) {
      int idx = t + i * 256;
      int r = idx >> 4, c = idx & 15;
      uint4 vv = make_uint4(0, 0, 0, 0);
      if (tb + r < n) vv = *(const uint4*)(hb + (size_t)(tb + r) * 128 + c * 8);
      *(uint4*)(&hs[r * 128 + ((c ^ (r & 7)) * 8)]) = vv;
    }
    __syncthreads();
    f32x4 acc[4];
#pragma unroll
    for (int ct = 0; ct < 4; ct++) acc[ct] = (f32x4){0.f, 0.f, 0.f, 0.f};
#pragma unroll
    for (int ks = 0; ks < 4; ks++) {
      int r = w * 16 + lr;
      int c = ks * 4 + lg;
      bf16x8 a = *(const bf16x8*)(&hs[r * 128 + ((c ^ (r & 7)) * 8)]);
#pragma unroll
      for (int ct = 0; ct < 4; ct++)
        acc[ct] = __builtin_amdgcn_mfma_f32_16x16x32_bf16(a, bfrag[ct][ks], acc[ct], 0, 0, 0);
    }
    // epilogue: x (bf16) + fused a_s/a_d
#pragma unroll
    for (int j = 0; j < 4; j++) {
      int row = tb + w * 16 + lg * 4 + j;
      bool ok = row < n;
      if (ok) {
#pragma unroll
        for (int ct = 0; ct < 4; ct++)
          xb[(size_t)row * 128 + ch * 64 + ct * 16 + lr] = f2bf(acc[ct][j]);
      }
      float psA = acc[0][j] * avs[0] + acc[1][j] * avs[1];
      float pdA = acc[0][j] * avd[0] + acc[1][j] * avd[1];
      float psB = acc[2][j] * avs[2] + acc[3][j] * avs[3];
      float pdB = acc[2][j] * avd[2] + acc[3][j] * avd[3];
#pragma unroll
      for (int m = 1; m <= 8; m <<= 1) {
        psA += __shfl_xor(psA, m); pdA += __shfl_xor(pdA, m);
        psB += __shfl_xor(psB, m); pdB += __shfl_xor(pdB, m);
      }
      if (lr == 0 && ok) {
        a_s[(size_t)row * 4 + ch * 2] = psA;
        a_s[(size_t)row * 4 + ch * 2 + 1] = psB;
        a_d[(size_t)row * 4 + ch * 2] = pdA;
        a_d[(size_t)row * 4 + ch * 2 + 1] = pdB;
      }
    }
  }
}

// -------- per-dst softmax (lane-parallel logits) + bf16 gather; lane owns cols 2l,2l+1 --------
__global__ void k_agg(const unsigned short* __restrict__ xb, const float* __restrict__ a_s,
                      const float* __restrict__ a_d, const float* __restrict__ ae,
                      const float* __restrict__ ae_loop,
                      const int* __restrict__ rowptr, const int* __restrict__ csr,
                      const int* __restrict__ srcarr, const float* __restrict__ bias,
                      float* __restrict__ hout, unsigned short* __restrict__ hbout,
                      int n, int l) {
  int wid = threadIdx.x >> 6;
  int v = blockIdx.x * 4 + wid;
  if (v >= n) return;
  int lane = threadIdx.x & 63;
  int el = lane >> 2;  // edge slot 0..15
  int hh = lane & 3;   // head for logit work
  float ad_own = a_d[(size_t)v * 4 + hh];
  float as_own = a_s[(size_t)v * 4 + hh];
  float aeL_own = ae_loop[(size_t)v * 12 + l * 4 + hh];
  float m_own = leaky02(as_own + ad_own + aeL_own);
  float s[4];
#pragma unroll
  for (int h2 = 0; h2 < 4; h2++) s[h2] = 1.f;
  int c2 = lane * 2;
  int headO = lane >> 4;  // head owning cols 2l,2l+1
  uint32 wv = *(const uint32*)(xb + (size_t)v * 128 + c2);
  float a0 = bf2f(wv & 0xffff);
  float a1 = bf2f(wv >> 16);
  int beg = rowptr[v], end = rowptr[v + 1];
  for (int cb = beg; cb < end; cb += 16) {
    int ne = end - cb;
    if (ne > 16) ne = 16;
    float logit = -1e30f;
    int srcE = 0;
    if (el < ne) {
      int eid = csr[cb + el];
      srcE = srcarr[eid];
      float asrc = a_s[(size_t)srcE * 4 + hh];
      float aev = ae[(size_t)eid * 12 + l * 4 + hh];
      logit = leaky02(asrc + ad_own + aev);
    }
    float cm = logit;
    cm = fmaxf(cm, __shfl_xor(cm, 4));
    cm = fmaxf(cm, __shfl_xor(cm, 8));
    cm = fmaxf(cm, __shfl_xor(cm, 16));
    cm = fmaxf(cm, __shfl_xor(cm, 32));
    float mn_own = fmaxf(m_own, cm);
    float p = (el < ne) ? __expf(logit - mn_own) : 0.f;
    float ps = p;
    ps += __shfl_xor(ps, 4);
    ps += __shfl_xor(ps, 8);
    ps += __shfl_xor(ps, 16);
    ps += __shfl_xor(ps, 32);
    float c_own = __expf(m_own - mn_own);
    m_own = mn_own;
    float c[4];
#pragma unroll
    for (int h2 = 0; h2 < 4; h2++) {
      c[h2] = __shfl(c_own, h2);
      s[h2] = s[h2] * c[h2] + __shfl(ps, h2);
    }
    float cO = (headO & 2) ? ((headO & 1) ? c[3] : c[2]) : ((headO & 1) ? c[1] : c[0]);
    a0 *= cO;
    a1 *= cO;
    for (int e = 0; e < ne; e++) {
      int se = __builtin_amdgcn_readlane(srcE, e * 4);
      float pC = __shfl(p, e * 4 + headO);
      uint32 xw = *(const uint32*)(xb + (size_t)se * 128 + c2);
      a0 += pC * bf2f(xw & 0xffff);
      a1 += pC * bf2f(xw >> 16);
    }
  }
  float sO = (headO & 2) ? ((headO & 1) ? s[3] : s[2]) : ((headO & 1) ? s[1] : s[0]);
  float r0 = fmaxf(a0 / sO + bias[l * HID + c2], 0.f);
  float r1 = fmaxf(a1 / sO + bias[l * HID + c2 + 1], 0.f);
  *(float2*)(hout + (size_t)v * HID + c2) = make_float2(r0, r1);
  uint32 pk = (uint32)f2bf(r0) | ((uint32)f2bf(r1) << 16);
  *(uint32*)(hbout + (size_t)v * HID + c2) = pk;
}

// ---------------- pooling: batch is sorted -> register accumulate, flush on change ----------------
__global__ void k_pool(const float* __restrict__ h, const int* __restrict__ batch,
                       float* __restrict__ g, int n) {
  int t = threadIdx.x;  // 128
  int per = (n + gridDim.x - 1) / gridDim.x;
  int start = blockIdx.x * per;
  int end = min(n, start + per);
  float acc = 0.f;
  int cur = -1;
  for (int v = start; v < end; v++) {
    int b = batch[v];
    if (b != cur) {
      if (cur >= 0) atomicAdd(&g[cur * 128 + t], acc);
      acc = 0.f;
      cur = b;
    }
    acc += h[(size_t)v * 128 + t];
  }
  if (cur >= 0) atomicAdd(&g[cur * 128 + t], acc);
}

// ---------------- head MLP on pooled g (8x128) ----------------
__global__ void k_head(const float* __restrict__ g, const float* __restrict__ Wr1,
                       const float* __restrict__ br1, const float* __restrict__ Wr2,
                       const float* __restrict__ br2, float* __restrict__ out, int G_) {
  __shared__ float gl[8 * 128];
  __shared__ float red[128];
  int t = threadIdx.x;  // 128
  for (int i = t; i < G_ * 128; i += 128) gl[i] = g[i];
  __syncthreads();
  for (int i = 0; i < G_; i++) {
    float acc = br1[t];
    for (int k = 0; k < 128; k++) acc += gl[i * 128 + k] * Wr1[k * 128 + t];
    float hv = fmaxf(acc, 0.f);
    red[t] = hv * Wr2[t];
    __syncthreads();
    if (t == 0) {
      float s = br2[0];
      for (int k = 0; k < 128; k++) s += red[k];
      out[i] = s;
    }
    __syncthreads();
  }
}

extern "C" void kernel_launch(void* const* d_in, const int* in_sizes, int n_in,
                              void* d_out, int out_size, void* d_ws, size_t ws_size,
                              hipStream_t stream) {
  const float* node_numeric = (const float*)d_in[0];
  const int* node_cat0 = (const int*)d_in[1];
  const int* node_cat1 = (const int*)d_in[2];
  const float* edge_numeric = (const float*)d_in[3];
  const int* edge_cat0 = (const int*)d_in[4];
  const int* edge_cat1 = (const int*)d_in[5];
  const int* edge_index = (const int*)d_in[6];
  const int* batch = (const int*)d_in[7];
  const float* recipe = (const float*)d_in[8];
  const float* emb_node0 = (const float*)d_in[9];
  const float* emb_node1 = (const float*)d_in[10];
  const float* emb_edge0 = (const float*)d_in[11];
  const float* emb_edge1 = (const float*)d_in[12];
  const float* W_in = (const float*)d_in[13];
  const float* b_in = (const float*)d_in[14];
  const float* W_edge = (const float*)d_in[15];
  const float* b_edge = (const float*)d_in[16];
  const float* gat_lin = (const float*)d_in[17];
  const float* gat_lin_edge = (const float*)d_in[18];
  const float* att_src = (const float*)d_in[19];
  const float* att_dst = (const float*)d_in[20];
  const float* att_edge = (const float*)d_in[21];
  const float* gat_bias = (const float*)d_in[22];
  const float* W_r1 = (const float*)d_in[23];
  const float* b_r1 = (const float*)d_in[24];
  const float* W_r2 = (const float*)d_in[25];
  const float* b_r2 = (const float*)d_in[26];

  int N = in_sizes[0] / 8;
  int E = in_sizes[3] / 4;
  int Gn = in_sizes[8] / 16;
  const int* srcArr = edge_index;
  const int* dstArr = edge_index + E;

  char* ws = (char*)d_ws;
  size_t o = 0;
  auto alloc = [&](size_t b) {
    char* p = ws + o;
    o = (o + b + 255) & ~(size_t)255;
    return p;
  };
  float* h = (float*)alloc((size_t)N * 128 * 4);              // f32 h (for pool)
  unsigned short* hbf = (unsigned short*)alloc((size_t)N * 128 * 2);  // bf16 h
  unsigned short* xbf = (unsigned short*)alloc((size_t)N * 128 * 2);  // bf16 x
  float* ae = (float*)alloc((size_t)E * 12 * 4);
  float* aeL = (float*)alloc((size_t)N * 12 * 4);
  float* a_s = (float*)alloc((size_t)N * 4 * 4);
  float* a_d = (float*)alloc((size_t)N * 4 * 4);
  float* P = (float*)alloc(216 * 4);
  float* q = (float*)alloc(12 * 4);
  int* cnt = (int*)alloc((size_t)N * 4);
  int* rowptr = (int*)alloc((size_t)(N + 1) * 4);
  int* cursor = (int*)alloc((size_t)N * 4);
  int* bsum = (int*)alloc(512 * 4);
  int* csr = (int*)alloc((size_t)E * 4);
  float* g = (float*)alloc((size_t)Gn * 128 * 4);
  (void)ws_size;

  (void)hipMemsetAsync(cnt, 0, (size_t)N * 4, stream);
  (void)hipMemsetAsync(g, 0, (size_t)Gn * 128 * 4, stream);

  int nbl = (N + 255) / 256;
  int ebl = (E + 255) / 256;

  k_enc<<<2048, 256, 0, stream>>>(node_numeric, node_cat0, node_cat1, batch, recipe,
                                  emb_node0, emb_node1, W_in, b_in, hbf, N);
  k_prep<<<1, 128, 0, stream>>>(gat_lin_edge, att_edge, W_edge, b_edge, P, q);
  k_deg<<<ebl, 256, 0, stream>>>(dstArr, cnt, E);
  k_ae<<<ebl, 256, 0, stream>>>(edge_numeric, edge_cat0, edge_cat1,
                                emb_edge0, emb_edge1, P, q, ae, E);
  k_scan1<<<nbl, 256, 0, stream>>>(cnt, rowptr, bsum, N);
  k_scan2<<<1, 512, 0, stream>>>(bsum, nbl);
  k_scan3<<<nbl, 256, 0, stream>>>(rowptr, bsum, cursor, N, E);
  k_fill<<<ebl, 256, 0, stream>>>(dstArr, cursor, csr, E);
  k_loopae<<<nbl, 256, 0, stream>>>(ae, rowptr, csr, aeL, N);

  for (int l = 0; l < 3; l++) {
    dim3 gx(256, 2);
    k_x<<<gx, 256, 0, stream>>>(hbf, gat_lin + l * 16384, att_src + l * 128,
                                att_dst + l * 128, xbf, a_s, a_d, N);
    k_agg<<<(N + 3) / 4, 256, 0, stream>>>(xbf, a_s, a_d, ae, aeL, rowptr, csr, srcArr,
                                           gat_bias, h, hbf, N, l);
  }
  k_pool<<<512, 128, 0, stream>>>(h, batch, g, N);
  k_head<<<1, 128, 0, stream>>>(g, W_r1, b_r1, W_r2, b_r2, (float*)d_out, Gn);
}